// Round 1
// baseline (756.578 us; speedup 1.0000x reference)
//
#include <hip/hip_runtime.h>
#include <math.h>

#define N_NODES_C 50000
#define N_EDGES_C 800000

// ---------------------------------------------------------------------------
// GEMM: C[M,N] = A[M,K] @ W[K,N] + bias   (fp32, BM=64 BN=32 BK=32, 256 thr)
// Each thread computes a 4x2 microtile. N must be a multiple of 32; K of 32.
// ---------------------------------------------------------------------------
__global__ __launch_bounds__(256) void gemm_bias(
    const float* __restrict__ A, const float* __restrict__ W,
    const float* __restrict__ bias, float* __restrict__ C,
    int M, int N, int K)
{
    const int BM = 64, BN = 32, BK = 32;
    __shared__ float As[BK][BM];   // [k][m]
    __shared__ float Ws[BK][BN];   // [k][n]
    int tid = threadIdx.x;
    int tx = tid & 15;       // col group (2 cols)
    int ty = tid >> 4;       // row group (4 rows)
    int r0 = blockIdx.x * BM;
    int c0 = blockIdx.y * BN;
    float acc[4][2] = {};

    for (int kb = 0; kb < K; kb += BK) {
        // A tile: 64 rows x 32 k = 512 float4 slots, 2 per thread
        #pragma unroll
        for (int t = 0; t < 2; ++t) {
            int slot = tid * 2 + t;        // 0..511
            int row  = slot >> 3;          // 0..63
            int kc   = (slot & 7) * 4;     // 0..28
            int gr = r0 + row; if (gr > M - 1) gr = M - 1;
            const float4 a = *reinterpret_cast<const float4*>(&A[(size_t)gr * K + kb + kc]);
            As[kc + 0][row] = a.x; As[kc + 1][row] = a.y;
            As[kc + 2][row] = a.z; As[kc + 3][row] = a.w;
        }
        // W tile: 32 k x 32 n = 256 float4 slots, 1 per thread
        {
            int row = tid >> 3;            // k 0..31
            int cc  = (tid & 7) * 4;       // 0..28
            *reinterpret_cast<float4*>(&Ws[row][cc]) =
                *reinterpret_cast<const float4*>(&W[(size_t)(kb + row) * N + c0 + cc]);
        }
        __syncthreads();
        #pragma unroll
        for (int kk = 0; kk < BK; ++kk) {
            float4 a = *reinterpret_cast<const float4*>(&As[kk][ty * 4]);
            float2 w = *reinterpret_cast<const float2*>(&Ws[kk][tx * 2]);
            acc[0][0] += a.x * w.x; acc[0][1] += a.x * w.y;
            acc[1][0] += a.y * w.x; acc[1][1] += a.y * w.y;
            acc[2][0] += a.z * w.x; acc[2][1] += a.z * w.y;
            acc[3][0] += a.w * w.x; acc[3][1] += a.w * w.y;
        }
        __syncthreads();
    }
    float2 b2 = *reinterpret_cast<const float2*>(&bias[c0 + tx * 2]);
    #pragma unroll
    for (int i = 0; i < 4; ++i) {
        int gr = r0 + ty * 4 + i;
        if (gr < M) {
            float2 o;
            o.x = acc[i][0] + b2.x;
            o.y = acc[i][1] + b2.y;
            *reinterpret_cast<float2*>(&C[(size_t)gr * N + c0 + tx * 2]) = o;
        }
    }
}

// ---------------------------------------------------------------------------
// CSR build: histogram -> single-block exclusive scan -> fill (atomics on int)
// ---------------------------------------------------------------------------
__global__ void count_kernel(const int* __restrict__ dst, int* __restrict__ cnt, int E)
{
    int e = blockIdx.x * blockDim.x + threadIdx.x;
    if (e < E) atomicAdd(&cnt[dst[e]], 1);
}

__global__ __launch_bounds__(1024) void scan_kernel(
    const int* __restrict__ cnt, int* __restrict__ row, int n)
{
    __shared__ int sm[1024];
    __shared__ int carry_s;
    if (threadIdx.x == 0) carry_s = 0;
    __syncthreads();
    for (int base = 0; base < n; base += 1024) {
        int i = base + (int)threadIdx.x;
        int val = (i < n) ? cnt[i] : 0;
        sm[threadIdx.x] = val;
        __syncthreads();
        for (int off = 1; off < 1024; off <<= 1) {
            int t = (threadIdx.x >= (unsigned)off) ? sm[threadIdx.x - off] : 0;
            __syncthreads();
            sm[threadIdx.x] += t;
            __syncthreads();
        }
        int incl  = sm[threadIdx.x];
        int carry = carry_s;
        if (i < n) row[i] = carry + incl - val;   // exclusive
        int total = sm[1023];
        __syncthreads();
        if (threadIdx.x == 0) carry_s += total;
        __syncthreads();
    }
    if (threadIdx.x == 0) row[n] = carry_s;
}

__global__ void copy_kernel(const int* __restrict__ a, int* __restrict__ b, int n)
{
    int i = blockIdx.x * blockDim.x + threadIdx.x;
    if (i < n) b[i] = a[i];
}

__global__ void fill_kernel(const int* __restrict__ src, const int* __restrict__ dst,
                            int* __restrict__ cursor, int* __restrict__ csr_src, int E)
{
    int e = blockIdx.x * blockDim.x + threadIdx.x;
    if (e < E) {
        int d = dst[e];
        int p = atomicAdd(&cursor[d], 1);
        csr_src[p] = src[e];
    }
}

// ---------------------------------------------------------------------------
// Fused per-node attention aggregate (online softmax, one wave per node).
// dims: 96 = lane(0..63) covers d<64, lanes 0..31 also cover d=64+lane.
// out[n] = (sum_e p_e * v[src_e]) / (sum_e p_e + 1e-16) + skip[n]  [, ReLU]
// ---------------------------------------------------------------------------
template<bool RELU>
__global__ __launch_bounds__(256) void aggregate_kernel(
    const float* __restrict__ q, const float* __restrict__ k,
    const float* __restrict__ v, const float* __restrict__ skip,
    const int* __restrict__ row, const int* __restrict__ csr_src,
    float* __restrict__ out, int nnodes)
{
    int wid  = threadIdx.x >> 6;
    int lane = threadIdx.x & 63;
    int n = blockIdx.x * 4 + wid;
    if (n >= nnodes) return;
    const float scale = 0.10206207261596577f;   // 1/sqrt(96)
    size_t base = (size_t)n * 96;
    float q0 = q[base + lane];
    float q1 = (lane < 32) ? q[base + 64 + lane] : 0.0f;

    float m = -INFINITY, s = 0.0f, acc0 = 0.0f, acc1 = 0.0f;
    int beg = row[n], end = row[n + 1];
    for (int i = beg; i < end; ++i) {
        int sc = csr_src[i];
        size_t sb = (size_t)sc * 96;
        float k0 = k[sb + lane];
        float k1 = (lane < 32) ? k[sb + 64 + lane] : 0.0f;
        float v0 = v[sb + lane];
        float v1 = (lane < 32) ? v[sb + 64 + lane] : 0.0f;
        float part = q0 * k0 + q1 * k1;
        #pragma unroll
        for (int off = 32; off; off >>= 1) part += __shfl_xor(part, off);
        float alpha = part * scale;
        float mn = fmaxf(m, alpha);
        float c  = expf(m - mn);       // 0 on first edge (m = -inf)
        float p  = expf(alpha - mn);
        s    = s    * c + p;
        acc0 = acc0 * c + p * v0;
        acc1 = acc1 * c + p * v1;
        m = mn;
    }
    float inv = 1.0f / (s + 1e-16f);
    float o0 = acc0 * inv + skip[base + lane];
    if (RELU) o0 = fmaxf(o0, 0.0f);
    out[base + lane] = o0;
    if (lane < 32) {
        float o1 = acc1 * inv + skip[base + 64 + lane];
        if (RELU) o1 = fmaxf(o1, 0.0f);
        out[base + 64 + lane] = o1;
    }
}

// ---------------------------------------------------------------------------
extern "C" void kernel_launch(void* const* d_in, const int* in_sizes, int n_in,
                              void* d_out, int out_size, void* d_ws, size_t ws_size,
                              hipStream_t stream)
{
    const int NN = N_NODES_C, NE = N_EDGES_C;
    const float* x  = (const float*)d_in[0];
    const int*   ei = (const int*)d_in[1];
    const int* src = ei;
    const int* dst = ei + NE;

    const float* Wq1 = (const float*)d_in[2];  const float* bq1 = (const float*)d_in[3];
    const float* Wk1 = (const float*)d_in[4];  const float* bk1 = (const float*)d_in[5];
    const float* Wv1 = (const float*)d_in[6];  const float* bv1 = (const float*)d_in[7];
    const float* Ws1 = (const float*)d_in[8];  const float* bs1 = (const float*)d_in[9];
    const float* Wq2 = (const float*)d_in[10]; const float* bq2 = (const float*)d_in[11];
    const float* Wk2 = (const float*)d_in[12]; const float* bk2 = (const float*)d_in[13];
    const float* Wv2 = (const float*)d_in[14]; const float* bv2 = (const float*)d_in[15];
    const float* Ws2 = (const float*)d_in[16]; const float* bs2 = (const float*)d_in[17];
    const float* Wd  = (const float*)d_in[18]; const float* bd  = (const float*)d_in[19];

    // workspace layout (floats): q | k | v | skip | h   then ints: row | cursor | csr_src
    float* f = (float*)d_ws;
    const size_t NQ = (size_t)NN * 96;
    float* qb = f;
    float* kb = f + NQ;
    float* vb = f + 2 * NQ;
    float* sb = f + 3 * NQ;
    float* hb = f + 4 * NQ;
    int* ip     = (int*)(f + 5 * NQ);
    int* rowp   = ip;                 // NN+1
    int* cursor = ip + (NN + 1);      // NN (doubles as counts)
    int* csr    = ip + (2 * NN + 1);  // NE

    // ---- CSR build (edge_index is the same every call; rebuilt since ws is poisoned)
    hipMemsetAsync(cursor, 0, NN * sizeof(int), stream);
    count_kernel<<<(NE + 255) / 256, 256, 0, stream>>>(dst, cursor, NE);
    scan_kernel<<<1, 1024, 0, stream>>>(cursor, rowp, NN);
    copy_kernel<<<(NN + 255) / 256, 256, 0, stream>>>(rowp, cursor, NN);
    fill_kernel<<<(NE + 255) / 256, 256, 0, stream>>>(src, dst, cursor, csr, NE);

    dim3 blk(256);
    dim3 g96((NN + 63) / 64, 96 / 32);
    dim3 g32((NN + 63) / 64, 1);
    int aggGrid = (NN + 3) / 4;

    // ---- layer 1: q/k/v/skip = x @ W + b  (K=128, N=96)
    gemm_bias<<<g96, blk, 0, stream>>>(x, Wq1, bq1, qb, NN, 96, 128);
    gemm_bias<<<g96, blk, 0, stream>>>(x, Wk1, bk1, kb, NN, 96, 128);
    gemm_bias<<<g96, blk, 0, stream>>>(x, Wv1, bv1, vb, NN, 96, 128);
    gemm_bias<<<g96, blk, 0, stream>>>(x, Ws1, bs1, sb, NN, 96, 128);
    aggregate_kernel<true><<<aggGrid, blk, 0, stream>>>(qb, kb, vb, sb, rowp, csr, hb, NN);

    // ---- layer 2: (K=96, N=96), input hb
    gemm_bias<<<g96, blk, 0, stream>>>(hb, Wq2, bq2, qb, NN, 96, 96);
    gemm_bias<<<g96, blk, 0, stream>>>(hb, Wk2, bk2, kb, NN, 96, 96);
    gemm_bias<<<g96, blk, 0, stream>>>(hb, Wv2, bv2, vb, NN, 96, 96);
    gemm_bias<<<g96, blk, 0, stream>>>(hb, Ws2, bs2, sb, NN, 96, 96);
    // output overwrites hb (not read by aggregate)
    aggregate_kernel<false><<<aggGrid, blk, 0, stream>>>(qb, kb, vb, sb, rowp, csr, hb, NN);

    // ---- head: d_out = hb @ Wd + bd  (K=96, N=32)
    gemm_bias<<<g32, blk, 0, stream>>>(hb, Wd, bd, (float*)d_out, NN, 32, 96);
}

// Round 3
// 549.778 us; speedup vs baseline: 1.3762x; 1.3762x over previous
//
#include <hip/hip_runtime.h>
#include <math.h>

#define N_NODES_C 50000
#define N_EDGES_C 800000

// ---------------------------------------------------------------------------
// Fused GEMM: C[M,N] = A[M,K] @ W[K,N] + bias. BM=BN=128, BK=32, 256 threads,
// 8x8 effective microtile (2x2 groups of 4x4), ~1 B LDS per FMA.
// Requires: N % 128 == 0, K % 32 == 0.
// ---------------------------------------------------------------------------
__global__ __launch_bounds__(256) void gemm128(
    const float* __restrict__ A, const float* __restrict__ W,
    const float* __restrict__ bias, float* __restrict__ C,
    int M, int N, int K)
{
    __shared__ float As[32][132];   // [k][row], padded stride (16B-aligned rows)
    __shared__ float Ws[32][128];   // [k][col]
    const int tid = threadIdx.x;
    const int tx = tid & 15;        // col group
    const int ty = tid >> 4;        // row group
    const int r0 = blockIdx.x * 128;
    const int c0 = blockIdx.y * 128;

    float acc[2][2][4][4];          // [rg][cg][ri][ci]
    #pragma unroll
    for (int a = 0; a < 2; ++a)
        #pragma unroll
        for (int b = 0; b < 2; ++b)
            #pragma unroll
            for (int i = 0; i < 4; ++i)
                #pragma unroll
                for (int j = 0; j < 4; ++j) acc[a][b][i][j] = 0.f;

    for (int kb = 0; kb < K; kb += 32) {
        // A tile: 128 rows x 32 k. 8 lanes cover one row's 32 floats (coalesced).
        #pragma unroll
        for (int p = 0; p < 4; ++p) {
            int row = (tid >> 3) + p * 32;
            int kc4 = tid & 7;
            int gr = r0 + row; if (gr > M - 1) gr = M - 1;
            float4 a = *reinterpret_cast<const float4*>(&A[(size_t)gr * K + kb + kc4 * 4]);
            As[kc4 * 4 + 0][row] = a.x;
            As[kc4 * 4 + 1][row] = a.y;
            As[kc4 * 4 + 2][row] = a.z;
            As[kc4 * 4 + 3][row] = a.w;
        }
        // W tile: 32 k x 128 cols (coalesced float4 rows)
        #pragma unroll
        for (int p = 0; p < 4; ++p) {
            int kr  = (tid >> 5) + p * 8;
            int cc4 = tid & 31;
            float4 w = *reinterpret_cast<const float4*>(&W[(size_t)(kb + kr) * N + c0 + cc4 * 4]);
            *reinterpret_cast<float4*>(&Ws[kr][cc4 * 4]) = w;
        }
        __syncthreads();
        #pragma unroll 4
        for (int kk = 0; kk < 32; ++kk) {
            float4 a0 = *reinterpret_cast<const float4*>(&As[kk][ty * 4]);
            float4 a1 = *reinterpret_cast<const float4*>(&As[kk][64 + ty * 4]);
            float4 w0 = *reinterpret_cast<const float4*>(&Ws[kk][tx * 4]);
            float4 w1 = *reinterpret_cast<const float4*>(&Ws[kk][64 + tx * 4]);
            const float ar[2][4] = {{a0.x, a0.y, a0.z, a0.w}, {a1.x, a1.y, a1.z, a1.w}};
            const float wc[2][4] = {{w0.x, w0.y, w0.z, w0.w}, {w1.x, w1.y, w1.z, w1.w}};
            #pragma unroll
            for (int rg = 0; rg < 2; ++rg)
                #pragma unroll
                for (int cg = 0; cg < 2; ++cg)
                    #pragma unroll
                    for (int ri = 0; ri < 4; ++ri)
                        #pragma unroll
                        for (int ci = 0; ci < 4; ++ci)
                            acc[rg][cg][ri][ci] += ar[rg][ri] * wc[cg][ci];
        }
        __syncthreads();
    }

    #pragma unroll
    for (int cg = 0; cg < 2; ++cg) {
        float4 bb = *reinterpret_cast<const float4*>(&bias[c0 + cg * 64 + tx * 4]);
        const float bc[4] = {bb.x, bb.y, bb.z, bb.w};
        #pragma unroll
        for (int rg = 0; rg < 2; ++rg)
            #pragma unroll
            for (int ri = 0; ri < 4; ++ri) {
                int r = r0 + rg * 64 + ty * 4 + ri;
                if (r < M) {
                    float4 o;
                    o.x = acc[rg][cg][ri][0] + bc[0];
                    o.y = acc[rg][cg][ri][1] + bc[1];
                    o.z = acc[rg][cg][ri][2] + bc[2];
                    o.w = acc[rg][cg][ri][3] + bc[3];
                    *reinterpret_cast<float4*>(&C[(size_t)r * N + c0 + cg * 64 + tx * 4]) = o;
                }
            }
    }
}

// ---------------------------------------------------------------------------
// Small GEMM for the head (N=32): 4x2 microtile, BM=64 BN=32 BK=32.
// ---------------------------------------------------------------------------
__global__ __launch_bounds__(256) void gemm_bias(
    const float* __restrict__ A, const float* __restrict__ W,
    const float* __restrict__ bias, float* __restrict__ C,
    int M, int N, int K)
{
    const int BM = 64, BN = 32, BK = 32;
    __shared__ float As[BK][BM];
    __shared__ float Ws[BK][BN];
    int tid = threadIdx.x;
    int tx = tid & 15;
    int ty = tid >> 4;
    int r0 = blockIdx.x * BM;
    int c0 = blockIdx.y * BN;
    float acc[4][2] = {};

    for (int kb = 0; kb < K; kb += BK) {
        #pragma unroll
        for (int t = 0; t < 2; ++t) {
            int slot = tid * 2 + t;
            int row  = slot >> 3;
            int kc   = (slot & 7) * 4;
            int gr = r0 + row; if (gr > M - 1) gr = M - 1;
            const float4 a = *reinterpret_cast<const float4*>(&A[(size_t)gr * K + kb + kc]);
            As[kc + 0][row] = a.x; As[kc + 1][row] = a.y;
            As[kc + 2][row] = a.z; As[kc + 3][row] = a.w;
        }
        {
            int row = tid >> 3;
            int cc  = (tid & 7) * 4;
            *reinterpret_cast<float4*>(&Ws[row][cc]) =
                *reinterpret_cast<const float4*>(&W[(size_t)(kb + row) * N + c0 + cc]);
        }
        __syncthreads();
        #pragma unroll
        for (int kk = 0; kk < BK; ++kk) {
            float4 a = *reinterpret_cast<const float4*>(&As[kk][ty * 4]);
            float2 w = *reinterpret_cast<const float2*>(&Ws[kk][tx * 2]);
            acc[0][0] += a.x * w.x; acc[0][1] += a.x * w.y;
            acc[1][0] += a.y * w.x; acc[1][1] += a.y * w.y;
            acc[2][0] += a.z * w.x; acc[2][1] += a.z * w.y;
            acc[3][0] += a.w * w.x; acc[3][1] += a.w * w.y;
        }
        __syncthreads();
    }
    float2 b2 = *reinterpret_cast<const float2*>(&bias[c0 + tx * 2]);
    #pragma unroll
    for (int i = 0; i < 4; ++i) {
        int gr = r0 + ty * 4 + i;
        if (gr < M) {
            float2 o;
            o.x = acc[i][0] + b2.x;
            o.y = acc[i][1] + b2.y;
            *reinterpret_cast<float2*>(&C[(size_t)gr * N + c0 + tx * 2]) = o;
        }
    }
}

// ---------------------------------------------------------------------------
// Weight/bias packing: [Wq|Wk|Wv|Ws] -> W4[K][384], biases -> b4[384]
// ---------------------------------------------------------------------------
__global__ void pack_w4(const float* __restrict__ w0, const float* __restrict__ w1,
                        const float* __restrict__ w2, const float* __restrict__ w3,
                        float* __restrict__ out, int K)
{
    int idx = blockIdx.x * blockDim.x + threadIdx.x;
    if (idx < K * 96) {
        int k = idx / 96, cc = idx - k * 96;
        float* o = out + (size_t)k * 384 + cc;
        o[0]   = w0[idx];
        o[96]  = w1[idx];
        o[192] = w2[idx];
        o[288] = w3[idx];
    }
}

__global__ void pack_b4(const float* __restrict__ b0, const float* __restrict__ b1,
                        const float* __restrict__ b2, const float* __restrict__ b3,
                        float* __restrict__ out)
{
    int i = threadIdx.x;   // 96 threads
    out[i] = b0[i]; out[96 + i] = b1[i]; out[192 + i] = b2[i]; out[288 + i] = b3[i];
}

// ---------------------------------------------------------------------------
// CSR build
// ---------------------------------------------------------------------------
__global__ void count_kernel(const int* __restrict__ dst, int* __restrict__ cnt, int E)
{
    int e = blockIdx.x * blockDim.x + threadIdx.x;
    if (e < E) atomicAdd(&cnt[dst[e]], 1);
}

__global__ __launch_bounds__(1024) void scan_kernel(
    const int* __restrict__ cnt, int* __restrict__ row, int n)
{
    __shared__ int wsum[16];
    __shared__ int carry_s;
    const int lane = threadIdx.x & 63;
    const int wid  = threadIdx.x >> 6;
    if (threadIdx.x == 0) carry_s = 0;
    __syncthreads();
    for (int base = 0; base < n; base += 1024) {
        const int i = base + (int)threadIdx.x;
        const int val = (i < n) ? cnt[i] : 0;
        int x = val;
        #pragma unroll
        for (int off = 1; off < 64; off <<= 1) {
            int t = __shfl_up(x, off);
            if (lane >= off) x += t;
        }
        if (lane == 63) wsum[wid] = x;
        __syncthreads();
        if (wid == 0) {
            int w = (lane < 16) ? wsum[lane] : 0;
            #pragma unroll
            for (int off = 1; off < 16; off <<= 1) {
                int t = __shfl_up(w, off);
                if (lane >= off) w += t;
            }
            if (lane < 16) wsum[lane] = w;
        }
        __syncthreads();
        const int carry = carry_s;
        const int woff = (wid > 0) ? wsum[wid - 1] : 0;
        if (i < n) row[i] = carry + woff + x - val;
        __syncthreads();
        if (threadIdx.x == 0) carry_s = carry + wsum[15];
        __syncthreads();
    }
    if (threadIdx.x == 0) row[n] = carry_s;
}

__global__ void copy_kernel(const int* __restrict__ a, int* __restrict__ b, int n)
{
    int i = blockIdx.x * blockDim.x + threadIdx.x;
    if (i < n) b[i] = a[i];
}

__global__ void fill_kernel(const int* __restrict__ src, const int* __restrict__ dst,
                            int* __restrict__ cursor, int* __restrict__ csr_src, int E)
{
    int e = blockIdx.x * blockDim.x + threadIdx.x;
    if (e < E) {
        int d = dst[e];
        int p = atomicAdd(&cursor[d], 1);
        csr_src[p] = src[e];
    }
}

// ---------------------------------------------------------------------------
// Fused attention aggregate. qkvs layout: [n][384] = q|k|v|skip (96 each).
// One wave per node; dims mapped 3x32 per half-wave; each half-wave handles a
// different edge per iteration (2 edges/iter, 5 shuffles total, max-free
// softmax -> fully reassociable accumulators). Unrolled 2 pairs (4 edges).
// ---------------------------------------------------------------------------
template<bool RELU>
__global__ __launch_bounds__(256) void aggregate_kernel(
    const float* __restrict__ qkvs, const int* __restrict__ row,
    const int* __restrict__ csr, float* __restrict__ out, int nnodes)
{
    const int wid  = threadIdx.x >> 6;
    const int lane = threadIdx.x & 63;
    const int c = lane & 31;        // dim within 32-chunk
    const int h = lane >> 5;        // half id (edge selector)
    const int n = blockIdx.x * 4 + wid;
    if (n >= nnodes) return;
    const float scale = 0.10206207261596577f;   // 1/sqrt(96)
    const size_t qb = (size_t)n * 384;
    const float q0 = qkvs[qb + c];
    const float q1 = qkvs[qb + 32 + c];
    const float q2 = qkvs[qb + 64 + c];

    float s = 0.f, a0 = 0.f, a1 = 0.f, a2 = 0.f;
    const int beg = row[n], end = row[n + 1];
    int i = beg;
    for (; i + 4 <= end; i += 4) {
        const int scA = csr[i + h];
        const int scB = csr[i + 2 + h];
        const size_t bA = (size_t)scA * 384;
        const size_t bB = (size_t)scB * 384;
        float kA0 = qkvs[bA + 96 + c],  kA1 = qkvs[bA + 128 + c], kA2 = qkvs[bA + 160 + c];
        float vA0 = qkvs[bA + 192 + c], vA1 = qkvs[bA + 224 + c], vA2 = qkvs[bA + 256 + c];
        float kB0 = qkvs[bB + 96 + c],  kB1 = qkvs[bB + 128 + c], kB2 = qkvs[bB + 160 + c];
        float vB0 = qkvs[bB + 192 + c], vB1 = qkvs[bB + 224 + c], vB2 = qkvs[bB + 256 + c];
        float pA = q0 * kA0 + q1 * kA1 + q2 * kA2;
        float pB = q0 * kB0 + q1 * kB1 + q2 * kB2;
        #pragma unroll
        for (int off = 1; off < 32; off <<= 1) {
            pA += __shfl_xor(pA, off);
            pB += __shfl_xor(pB, off);
        }
        float eA = __expf(pA * scale);
        float eB = __expf(pB * scale);
        s  += eA + eB;
        a0 += eA * vA0 + eB * vB0;
        a1 += eA * vA1 + eB * vB1;
        a2 += eA * vA2 + eB * vB2;
    }
    for (; i < end; i += 2) {
        const int j = i + h;
        const int jc = (j < end) ? j : (end - 1);
        const int sc = csr[jc];
        const size_t b = (size_t)sc * 384;
        float k0 = qkvs[b + 96 + c],  k1 = qkvs[b + 128 + c], k2 = qkvs[b + 160 + c];
        float v0 = qkvs[b + 192 + c], v1 = qkvs[b + 224 + c], v2 = qkvs[b + 256 + c];
        float p = q0 * k0 + q1 * k1 + q2 * k2;
        #pragma unroll
        for (int off = 1; off < 32; off <<= 1) p += __shfl_xor(p, off);
        float e = (j < end) ? __expf(p * scale) : 0.f;
        s += e; a0 += e * v0; a1 += e * v1; a2 += e * v2;
    }
    // combine the two halves
    s  += __shfl_xor(s, 32);
    a0 += __shfl_xor(a0, 32);
    a1 += __shfl_xor(a1, 32);
    a2 += __shfl_xor(a2, 32);
    const float inv = 1.0f / (s + 1e-16f);
    if (lane < 32) {
        float o0 = a0 * inv + qkvs[qb + 288 + c];
        float o1 = a1 * inv + qkvs[qb + 320 + c];
        float o2 = a2 * inv + qkvs[qb + 352 + c];
        if (RELU) { o0 = fmaxf(o0, 0.f); o1 = fmaxf(o1, 0.f); o2 = fmaxf(o2, 0.f); }
        const size_t ob = (size_t)n * 96;
        out[ob + c] = o0; out[ob + 32 + c] = o1; out[ob + 64 + c] = o2;
    }
}

// ---------------------------------------------------------------------------
extern "C" void kernel_launch(void* const* d_in, const int* in_sizes, int n_in,
                              void* d_out, int out_size, void* d_ws, size_t ws_size,
                              hipStream_t stream)
{
    const int NN = N_NODES_C, NE = N_EDGES_C;
    const float* x  = (const float*)d_in[0];
    const int*   ei = (const int*)d_in[1];
    const int* src = ei;
    const int* dst = ei + NE;

    const float* Wq1 = (const float*)d_in[2];  const float* bq1 = (const float*)d_in[3];
    const float* Wk1 = (const float*)d_in[4];  const float* bk1 = (const float*)d_in[5];
    const float* Wv1 = (const float*)d_in[6];  const float* bv1 = (const float*)d_in[7];
    const float* Ws1 = (const float*)d_in[8];  const float* bs1 = (const float*)d_in[9];
    const float* Wq2 = (const float*)d_in[10]; const float* bq2 = (const float*)d_in[11];
    const float* Wk2 = (const float*)d_in[12]; const float* bk2 = (const float*)d_in[13];
    const float* Wv2 = (const float*)d_in[14]; const float* bv2 = (const float*)d_in[15];
    const float* Ws2 = (const float*)d_in[16]; const float* bs2 = (const float*)d_in[17];
    const float* Wd  = (const float*)d_in[18]; const float* bd  = (const float*)d_in[19];

    // workspace layout
    float* f = (float*)d_ws;
    size_t off = 0;
    float* qkvs = f + off;  off += (size_t)NN * 384;
    float* hb   = f + off;  off += (size_t)NN * 96;
    float* W4a  = f + off;  off += (size_t)128 * 384;
    float* W4b  = f + off;  off += (size_t)96 * 384;
    float* b4a  = f + off;  off += 384;
    float* b4b  = f + off;  off += 384;
    int* ip     = (int*)(f + off);
    int* rowp   = ip;                 // NN+1
    int* cursor = ip + (NN + 1);      // NN
    int* csr    = ip + (2 * NN + 1);  // NE

    // ---- CSR build
    hipMemsetAsync(cursor, 0, NN * sizeof(int), stream);
    count_kernel<<<(NE + 255) / 256, 256, 0, stream>>>(dst, cursor, NE);
    scan_kernel<<<1, 1024, 0, stream>>>(cursor, rowp, NN);
    copy_kernel<<<(NN + 255) / 256, 256, 0, stream>>>(rowp, cursor, NN);
    fill_kernel<<<(NE + 255) / 256, 256, 0, stream>>>(src, dst, cursor, csr, NE);

    // ---- weight packing
    pack_w4<<<(128 * 96 + 255) / 256, 256, 0, stream>>>(Wq1, Wk1, Wv1, Ws1, W4a, 128);
    pack_w4<<<(96 * 96 + 255) / 256, 256, 0, stream>>>(Wq2, Wk2, Wv2, Ws2, W4b, 96);
    pack_b4<<<1, 96, 0, stream>>>(bq1, bk1, bv1, bs1, b4a);
    pack_b4<<<1, 96, 0, stream>>>(bq2, bk2, bv2, bs2, b4b);

    dim3 blk(256);
    dim3 gg((NN + 127) / 128, 384 / 128);
    int aggGrid = (NN + 3) / 4;

    // ---- layer 1
    gemm128<<<gg, blk, 0, stream>>>(x, W4a, b4a, qkvs, NN, 384, 128);
    aggregate_kernel<true><<<aggGrid, blk, 0, stream>>>(qkvs, rowp, csr, hb, NN);

    // ---- layer 2
    gemm128<<<gg, blk, 0, stream>>>(hb, W4b, b4b, qkvs, NN, 384, 96);
    aggregate_kernel<false><<<aggGrid, blk, 0, stream>>>(qkvs, rowp, csr, hb, NN);

    // ---- head
    dim3 g32((NN + 63) / 64, 1);
    gemm_bias<<<g32, blk, 0, stream>>>(hb, Wd, bd, (float*)d_out, NN, 32, 96);
}

// Round 4
// 417.707 us; speedup vs baseline: 1.8113x; 1.3162x over previous
//
#include <hip/hip_runtime.h>
#include <hip/hip_bf16.h>
#include <math.h>

#define N_NODES_C 50000
#define N_EDGES_C 800000

typedef short bf16x8 __attribute__((ext_vector_type(8)));
typedef float f32x4 __attribute__((ext_vector_type(4)));

__device__ inline float blo(unsigned int u) { return __uint_as_float(u << 16); }
__device__ inline float bhi(unsigned int u) { return __uint_as_float(u & 0xffff0000u); }

__device__ inline unsigned short bf16rne(float f) {
    union { __hip_bfloat16 h; unsigned short u; } c;
    c.h = __float2bfloat16(f);
    return c.u;
}
__device__ inline unsigned int pk2(float a, float b) {
    return (unsigned int)bf16rne(a) | ((unsigned int)bf16rne(b) << 16);
}

// ---------------------------------------------------------------------------
// MFMA GEMM: C[M,384](bf16) = A[M,128](bf16) @ Wt[384,128]^T (bf16) + bias.
// K=128 fully staged in LDS. BM=BN=128, 4 waves (2x2), 4x4 16x16x32 frags per
// wave. XOR swizzle (byte ^ (row&7)<<4) on both LDS write and read sides.
// ---------------------------------------------------------------------------
__global__ __launch_bounds__(256) void gemm_mfma(
    const unsigned short* __restrict__ A, const unsigned short* __restrict__ Wt,
    const float* __restrict__ bias, unsigned short* __restrict__ C,
    int M, int N)
{
    __shared__ char lds[65536];
    char* sA = lds;
    char* sB = lds + 32768;
    const int tid = threadIdx.x;
    const int r0 = blockIdx.x * 128;
    const int c0 = blockIdx.y * 128;
    const char* Ab = (const char*)A;
    const char* Wb = (const char*)Wt + (size_t)c0 * 256;

    // stage A tile (rows r0..r0+127, 256 B/row), clamped at M-1
    #pragma unroll
    for (int sct = 0; sct < 8; ++sct) {
        int o = (sct * 256 + tid) * 16;
        int r = o >> 8;
        int gr = r0 + r; if (gr > M - 1) gr = M - 1;
        uint4 val = *reinterpret_cast<const uint4*>(Ab + (size_t)gr * 256 + (o & 255));
        *reinterpret_cast<uint4*>(sA + (o ^ ((r & 7) << 4))) = val;
    }
    // stage B tile (Wt rows c0..c0+127): contiguous 32 KB
    #pragma unroll
    for (int sct = 0; sct < 8; ++sct) {
        int o = (sct * 256 + tid) * 16;
        int r = o >> 8;
        uint4 val = *reinterpret_cast<const uint4*>(Wb + o);
        *reinterpret_cast<uint4*>(sB + (o ^ ((r & 7) << 4))) = val;
    }
    __syncthreads();

    const int lane = tid & 63, wid = tid >> 6;
    const int wm = wid >> 1, wn = wid & 1;
    const int qw = lane >> 4, c16 = lane & 15;

    f32x4 acc[4][4];
    #pragma unroll
    for (int a = 0; a < 4; ++a)
        #pragma unroll
        for (int b = 0; b < 4; ++b) acc[a][b] = (f32x4){0.f, 0.f, 0.f, 0.f};

    int aoff[4], boff[4];
    #pragma unroll
    for (int fm = 0; fm < 4; ++fm) {
        int r = wm * 64 + fm * 16 + c16;
        aoff[fm] = r * 256 + ((qw * 16) ^ ((r & 7) << 4));
    }
    #pragma unroll
    for (int fn = 0; fn < 4; ++fn) {
        int r = wn * 64 + fn * 16 + c16;
        boff[fn] = r * 256 + ((qw * 16) ^ ((r & 7) << 4));
    }

    #pragma unroll
    for (int ks = 0; ks < 4; ++ks) {
        const int kx = ks * 64;   // byte advance per k-step; XOR-safe (bits 6-7)
        bf16x8 af[4], bfr[4];
        #pragma unroll
        for (int fm = 0; fm < 4; ++fm)
            af[fm] = *reinterpret_cast<const bf16x8*>(sA + (aoff[fm] ^ kx));
        #pragma unroll
        for (int fn = 0; fn < 4; ++fn)
            bfr[fn] = *reinterpret_cast<const bf16x8*>(sB + (boff[fn] ^ kx));
        #pragma unroll
        for (int fm = 0; fm < 4; ++fm)
            #pragma unroll
            for (int fn = 0; fn < 4; ++fn)
                acc[fm][fn] = __builtin_amdgcn_mfma_f32_16x16x32_bf16(
                    af[fm], bfr[fn], acc[fm][fn], 0, 0, 0);
    }

    // epilogue: C/D layout col=lane&15, row=(lane>>4)*4+j. Pair adjacent cols
    // via shfl_xor(1), even lanes store one dword (2 bf16).
    char* Cb = (char*)C;
    float bcol[4];
    #pragma unroll
    for (int fn = 0; fn < 4; ++fn) bcol[fn] = bias[c0 + wn * 64 + fn * 16 + c16];
    #pragma unroll
    for (int fm = 0; fm < 4; ++fm) {
        #pragma unroll
        for (int fn = 0; fn < 4; ++fn) {
            #pragma unroll
            for (int j = 0; j < 4; ++j) {
                int rg = r0 + wm * 64 + fm * 16 + qw * 4 + j;
                float o = acc[fm][fn][j] + bcol[fn];
                float o2 = __shfl_xor(o, 1);
                if (!(lane & 1) && rg < M) {
                    int col = c0 + wn * 64 + fn * 16 + c16;
                    *reinterpret_cast<unsigned int*>(
                        Cb + (size_t)rg * (size_t)(N * 2) + (size_t)col * 2) = pk2(o, o2);
                }
            }
        }
    }
}

// ---------------------------------------------------------------------------
// Small fp32 GEMM for the head (N=32): 4x2 microtile, BM=64 BN=32 BK=32.
// ---------------------------------------------------------------------------
__global__ __launch_bounds__(256) void gemm_bias(
    const float* __restrict__ A, const float* __restrict__ W,
    const float* __restrict__ bias, float* __restrict__ C,
    int M, int N, int K)
{
    const int BM = 64, BN = 32, BK = 32;
    __shared__ float As[BK][BM];
    __shared__ float Ws[BK][BN];
    int tid = threadIdx.x;
    int tx = tid & 15;
    int ty = tid >> 4;
    int r0 = blockIdx.x * BM;
    int c0 = blockIdx.y * BN;
    float acc[4][2] = {};

    for (int kb = 0; kb < K; kb += BK) {
        #pragma unroll
        for (int t = 0; t < 2; ++t) {
            int slot = tid * 2 + t;
            int row  = slot >> 3;
            int kc   = (slot & 7) * 4;
            int gr = r0 + row; if (gr > M - 1) gr = M - 1;
            const float4 a = *reinterpret_cast<const float4*>(&A[(size_t)gr * K + kb + kc]);
            As[kc + 0][row] = a.x; As[kc + 1][row] = a.y;
            As[kc + 2][row] = a.z; As[kc + 3][row] = a.w;
        }
        {
            int row = tid >> 3;
            int cc  = (tid & 7) * 4;
            *reinterpret_cast<float4*>(&Ws[row][cc]) =
                *reinterpret_cast<const float4*>(&W[(size_t)(kb + row) * N + c0 + cc]);
        }
        __syncthreads();
        #pragma unroll
        for (int kk = 0; kk < BK; ++kk) {
            float4 a = *reinterpret_cast<const float4*>(&As[kk][ty * 4]);
            float2 w = *reinterpret_cast<const float2*>(&Ws[kk][tx * 2]);
            acc[0][0] += a.x * w.x; acc[0][1] += a.x * w.y;
            acc[1][0] += a.y * w.x; acc[1][1] += a.y * w.y;
            acc[2][0] += a.z * w.x; acc[2][1] += a.z * w.y;
            acc[3][0] += a.w * w.x; acc[3][1] += a.w * w.y;
        }
        __syncthreads();
    }
    float2 b2 = *reinterpret_cast<const float2*>(&bias[c0 + tx * 2]);
    #pragma unroll
    for (int i = 0; i < 4; ++i) {
        int gr = r0 + ty * 4 + i;
        if (gr < M) {
            float2 o;
            o.x = acc[i][0] + b2.x;
            o.y = acc[i][1] + b2.y;
            *reinterpret_cast<float2*>(&C[(size_t)gr * N + c0 + tx * 2]) = o;
        }
    }
}

// ---------------------------------------------------------------------------
// fp32 -> bf16 convert (x input)
// ---------------------------------------------------------------------------
__global__ void cvt_x(const float* __restrict__ in, unsigned short* __restrict__ out, int n4)
{
    int i = blockIdx.x * blockDim.x + threadIdx.x;
    if (i < n4) {
        float4 v = reinterpret_cast<const float4*>(in)[i];
        union { unsigned short s[4]; uint2 u; } cv;
        cv.s[0] = bf16rne(v.x); cv.s[1] = bf16rne(v.y);
        cv.s[2] = bf16rne(v.z); cv.s[3] = bf16rne(v.w);
        reinterpret_cast<uint2*>(out)[i] = cv.u;
    }
}

// ---------------------------------------------------------------------------
// Pack weights transposed + bf16: Wt[384][128]; Wt[n][k] = Wg[k][n%96] (0 for
// k >= K). Also packs fp32 bias b4[384].
// ---------------------------------------------------------------------------
__global__ void pack_wt(const float* __restrict__ w0, const float* __restrict__ w1,
                        const float* __restrict__ w2, const float* __restrict__ w3,
                        const float* __restrict__ b0, const float* __restrict__ b1,
                        const float* __restrict__ b2, const float* __restrict__ b3,
                        unsigned short* __restrict__ Wt, float* __restrict__ b4, int K)
{
    int idx = blockIdx.x * blockDim.x + threadIdx.x;
    if (idx < 384 * 128) {
        int n = idx >> 7, k = idx & 127;
        int g = n / 96, c = n - g * 96;
        const float* w = (g == 0) ? w0 : (g == 1) ? w1 : (g == 2) ? w2 : w3;
        float v = (k < K) ? w[(size_t)k * 96 + c] : 0.f;
        Wt[idx] = bf16rne(v);
        if (k == 0) {
            const float* bb = (g == 0) ? b0 : (g == 1) ? b1 : (g == 2) ? b2 : b3;
            b4[n] = bb[c];
        }
    }
}

// ---------------------------------------------------------------------------
// CSR build
// ---------------------------------------------------------------------------
__global__ void count_kernel(const int* __restrict__ dst, int* __restrict__ cnt, int E)
{
    int e = blockIdx.x * blockDim.x + threadIdx.x;
    if (e < E) atomicAdd(&cnt[dst[e]], 1);
}

__global__ __launch_bounds__(1024) void scan_kernel(
    const int* __restrict__ cnt, int* __restrict__ row, int n)
{
    __shared__ int wsum[16];
    __shared__ int carry_s;
    const int lane = threadIdx.x & 63;
    const int wid  = threadIdx.x >> 6;
    if (threadIdx.x == 0) carry_s = 0;
    __syncthreads();
    for (int base = 0; base < n; base += 1024) {
        const int i = base + (int)threadIdx.x;
        const int val = (i < n) ? cnt[i] : 0;
        int x = val;
        #pragma unroll
        for (int off = 1; off < 64; off <<= 1) {
            int t = __shfl_up(x, off);
            if (lane >= off) x += t;
        }
        if (lane == 63) wsum[wid] = x;
        __syncthreads();
        if (wid == 0) {
            int w = (lane < 16) ? wsum[lane] : 0;
            #pragma unroll
            for (int off = 1; off < 16; off <<= 1) {
                int t = __shfl_up(w, off);
                if (lane >= off) w += t;
            }
            if (lane < 16) wsum[lane] = w;
        }
        __syncthreads();
        const int carry = carry_s;
        const int woff = (wid > 0) ? wsum[wid - 1] : 0;
        if (i < n) row[i] = carry + woff + x - val;
        __syncthreads();
        if (threadIdx.x == 0) carry_s = carry + wsum[15];
        __syncthreads();
    }
    if (threadIdx.x == 0) row[n] = carry_s;
}

__global__ void copy_kernel(const int* __restrict__ a, int* __restrict__ b, int n)
{
    int i = blockIdx.x * blockDim.x + threadIdx.x;
    if (i < n) b[i] = a[i];
}

__global__ void fill_kernel(const int* __restrict__ src, const int* __restrict__ dst,
                            int* __restrict__ cursor, int* __restrict__ csr_src, int E)
{
    int e = blockIdx.x * blockDim.x + threadIdx.x;
    if (e < E) {
        int d = dst[e];
        int p = atomicAdd(&cursor[d], 1);
        csr_src[p] = src[e];
    }
}

// ---------------------------------------------------------------------------
// Fused attention aggregate, bf16 qkvs [n][384] = q|k|v|s (768 B rows).
// Half-wave (32 lanes) per edge, 2 edges/wave-iter. Lane c: dword = dims
// {2c,2c+1} of k and v; lanes 0-15 also carry k dims 64-95, lanes 16-31 carry
// v dims 64-95 (xb slot). Max-free softmax, fully reassociable accumulators.
// MODE 0: relu + bf16[128] zero-padded out. MODE 1: f32[96] out.
// ---------------------------------------------------------------------------
template<int MODE>
__global__ __launch_bounds__(256) void aggregate_kernel(
    const unsigned short* __restrict__ qkvs, const int* __restrict__ row,
    const int* __restrict__ csr, void* __restrict__ outv, int nnodes)
{
    const int wid  = threadIdx.x >> 6;
    const int lane = threadIdx.x & 63;
    const int c = lane & 31;
    const int h = lane >> 5;
    const int n = blockIdx.x * 4 + wid;
    if (n >= nnodes) return;
    const float scale = 0.10206207261596577f;   // 1/sqrt(96)
    const char* P = (const char*)qkvs;
    const size_t rb = (size_t)n * 768;

    const unsigned int qa = *(const unsigned int*)(P + rb + 4 * c);
    const unsigned int qbu = *(const unsigned int*)(P + rb + 128 + 4 * (c & 15));
    const float qalo = blo(qa), qahi = bhi(qa);
    float qblo, qbhi;
    if (c < 16) { qblo = blo(qbu); qbhi = bhi(qbu); } else { qblo = 0.f; qbhi = 0.f; }
    const int xsel = (c < 16) ? 320 : 448;   // k dims 64-95 | v dims 64-95

    float s = 0.f, alo = 0.f, ahi = 0.f, xlo = 0.f, xhi = 0.f;
    const int beg = row[n], end = row[n + 1];
    int i = beg;
    for (; i + 4 <= end; i += 4) {
        const int s0 = csr[i + h], s1 = csr[i + 2 + h];
        const size_t b0 = (size_t)s0 * 768, b1 = (size_t)s1 * 768;
        unsigned int ka0 = *(const unsigned int*)(P + b0 + 192 + 4 * c);
        unsigned int xb0 = *(const unsigned int*)(P + b0 + xsel + 4 * c);
        unsigned int va0 = *(const unsigned int*)(P + b0 + 384 + 4 * c);
        unsigned int ka1 = *(const unsigned int*)(P + b1 + 192 + 4 * c);
        unsigned int xb1 = *(const unsigned int*)(P + b1 + xsel + 4 * c);
        unsigned int va1 = *(const unsigned int*)(P + b1 + 384 + 4 * c);
        float p0 = qalo * blo(ka0) + qahi * bhi(ka0) + qblo * blo(xb0) + qbhi * bhi(xb0);
        float p1 = qalo * blo(ka1) + qahi * bhi(ka1) + qblo * blo(xb1) + qbhi * bhi(xb1);
        #pragma unroll
        for (int off = 1; off < 32; off <<= 1) {
            p0 += __shfl_xor(p0, off);
            p1 += __shfl_xor(p1, off);
        }
        float e0 = __expf(p0 * scale);
        float e1 = __expf(p1 * scale);
        float eb0 = (c >= 16) ? e0 : 0.f;
        float eb1 = (c >= 16) ? e1 : 0.f;
        s   += e0 + e1;
        alo += e0 * blo(va0) + e1 * blo(va1);
        ahi += e0 * bhi(va0) + e1 * bhi(va1);
        xlo += eb0 * blo(xb0) + eb1 * blo(xb1);
        xhi += eb0 * bhi(xb0) + eb1 * bhi(xb1);
    }
    for (; i < end; i += 2) {
        const int j = i + h;
        const int jc = (j < end) ? j : (end - 1);
        const int sc = csr[jc];
        const size_t b = (size_t)sc * 768;
        unsigned int ka = *(const unsigned int*)(P + b + 192 + 4 * c);
        unsigned int xb = *(const unsigned int*)(P + b + xsel + 4 * c);
        unsigned int va = *(const unsigned int*)(P + b + 384 + 4 * c);
        float p = qalo * blo(ka) + qahi * bhi(ka) + qblo * blo(xb) + qbhi * bhi(xb);
        #pragma unroll
        for (int off = 1; off < 32; off <<= 1) p += __shfl_xor(p, off);
        float e = (j < end) ? __expf(p * scale) : 0.f;
        float eb = (c >= 16) ? e : 0.f;
        s += e;
        alo += e * blo(va); ahi += e * bhi(va);
        xlo += eb * blo(xb); xhi += eb * bhi(xb);
    }
    s   += __shfl_xor(s, 32);
    alo += __shfl_xor(alo, 32);
    ahi += __shfl_xor(ahi, 32);
    xlo += __shfl_xor(xlo, 32);
    xhi += __shfl_xor(xhi, 32);
    const float inv = 1.0f / (s + 1e-16f);

    if (lane < 32) {
        const unsigned int sa = *(const unsigned int*)(P + rb + 576 + 4 * c);
        float o0 = alo * inv + blo(sa);
        float o1 = ahi * inv + bhi(sa);
        if (MODE == 0) {
            o0 = fmaxf(o0, 0.f); o1 = fmaxf(o1, 0.f);
            char* O = (char*)outv;
            const size_t ob = (size_t)n * 256;
            *(unsigned int*)(O + ob + 4 * c) = pk2(o0, o1);
            if (c >= 16) {
                const unsigned int sx = *(const unsigned int*)(P + rb + 640 + 4 * c);
                float ox0 = fmaxf(xlo * inv + blo(sx), 0.f);
                float ox1 = fmaxf(xhi * inv + bhi(sx), 0.f);
                *(unsigned int*)(O + ob + 64 + 4 * c) = pk2(ox0, ox1);
            } else {
                *(unsigned int*)(O + ob + 192 + 4 * c) = 0u;   // zero-pad dims 96-127
            }
        } else {
            char* O = (char*)outv;
            const size_t ob = (size_t)n * 384;
            *(float2*)(O + ob + 8 * c) = make_float2(o0, o1);
            if (c >= 16) {
                const unsigned int sx = *(const unsigned int*)(P + rb + 640 + 4 * c);
                float ox0 = xlo * inv + blo(sx);
                float ox1 = xhi * inv + bhi(sx);
                *(float2*)(O + ob + 128 + 8 * c) = make_float2(ox0, ox1);
            }
        }
    }
}

// ---------------------------------------------------------------------------
extern "C" void kernel_launch(void* const* d_in, const int* in_sizes, int n_in,
                              void* d_out, int out_size, void* d_ws, size_t ws_size,
                              hipStream_t stream)
{
    const int NN = N_NODES_C, NE = N_EDGES_C;
    const float* x  = (const float*)d_in[0];
    const int*   ei = (const int*)d_in[1];
    const int* src = ei;
    const int* dst = ei + NE;

    const float* Wq1 = (const float*)d_in[2];  const float* bq1 = (const float*)d_in[3];
    const float* Wk1 = (const float*)d_in[4];  const float* bk1 = (const float*)d_in[5];
    const float* Wv1 = (const float*)d_in[6];  const float* bv1 = (const float*)d_in[7];
    const float* Ws1 = (const float*)d_in[8];  const float* bs1 = (const float*)d_in[9];
    const float* Wq2 = (const float*)d_in[10]; const float* bq2 = (const float*)d_in[11];
    const float* Wk2 = (const float*)d_in[12]; const float* bk2 = (const float*)d_in[13];
    const float* Wv2 = (const float*)d_in[14]; const float* bv2 = (const float*)d_in[15];
    const float* Ws2 = (const float*)d_in[16]; const float* bs2 = (const float*)d_in[17];
    const float* Wd  = (const float*)d_in[18]; const float* bd  = (const float*)d_in[19];

    // byte-addressed workspace carve-up (all chunks 256-B aligned)
    char* base = (char*)d_ws;
    size_t off = 0;
    auto alloc = [&](size_t bytes) -> void* {
        void* p = base + off;
        off += (bytes + 255) & ~(size_t)255;
        return p;
    };
    unsigned short* xb16   = (unsigned short*)alloc((size_t)NN * 128 * 2);
    unsigned short* qkvs16 = (unsigned short*)alloc((size_t)NN * 384 * 2);
    unsigned short* hb16   = (unsigned short*)alloc((size_t)NN * 128 * 2);
    float*          h2f    = (float*)alloc((size_t)NN * 96 * 4);
    unsigned short* Wt4a   = (unsigned short*)alloc(384 * 128 * 2);
    unsigned short* Wt4b   = (unsigned short*)alloc(384 * 128 * 2);
    float*          b4a    = (float*)alloc(384 * 4);
    float*          b4b    = (float*)alloc(384 * 4);
    int*            rowp   = (int*)alloc((NN + 1) * 4);
    int*            cursor = (int*)alloc(NN * 4);
    int*            csr    = (int*)alloc((size_t)NE * 4);

    // ---- input conversion + weight packing
    cvt_x<<<(NN * 128 / 4 + 255) / 256, 256, 0, stream>>>(x, xb16, NN * 128 / 4);
    pack_wt<<<192, 256, 0, stream>>>(Wq1, Wk1, Wv1, Ws1, bq1, bk1, bv1, bs1, Wt4a, b4a, 128);
    pack_wt<<<192, 256, 0, stream>>>(Wq2, Wk2, Wv2, Ws2, bq2, bk2, bv2, bs2, Wt4b, b4b, 96);

    // ---- CSR build
    hipMemsetAsync(cursor, 0, NN * sizeof(int), stream);
    count_kernel<<<(NE + 255) / 256, 256, 0, stream>>>(dst, cursor, NE);
    scan_kernel<<<1, 1024, 0, stream>>>(cursor, rowp, NN);
    copy_kernel<<<(NN + 255) / 256, 256, 0, stream>>>(rowp, cursor, NN);
    fill_kernel<<<(NE + 255) / 256, 256, 0, stream>>>(src, dst, cursor, csr, NE);

    dim3 blk(256);
    dim3 gg((NN + 127) / 128, 3);
    int aggGrid = (NN + 3) / 4;

    // ---- layer 1
    gemm_mfma<<<gg, blk, 0, stream>>>(xb16, Wt4a, b4a, qkvs16, NN, 384);
    aggregate_kernel<0><<<aggGrid, blk, 0, stream>>>(qkvs16, rowp, csr, hb16, NN);

    // ---- layer 2 (K zero-padded 96->128)
    gemm_mfma<<<gg, blk, 0, stream>>>(hb16, Wt4b, b4b, qkvs16, NN, 384);
    aggregate_kernel<1><<<aggGrid, blk, 0, stream>>>(qkvs16, rowp, csr, h2f, NN);

    // ---- head (fp32): d_out = h2f @ Wd + bd
    dim3 g32((NN + 63) / 64, 1);
    gemm_bias<<<g32, blk, 0, stream>>>(h2f, Wd, bd, (float*)d_out, NN, 32, 96);
}

// Round 5
// 351.016 us; speedup vs baseline: 2.1554x; 1.1900x over previous
//
#include <hip/hip_runtime.h>
#include <hip/hip_bf16.h>
#include <math.h>

#define N_NODES_C 50000
#define N_EDGES_C 800000

typedef short bf16x8 __attribute__((ext_vector_type(8)));
typedef float f32x4 __attribute__((ext_vector_type(4)));

__device__ inline float blo(unsigned int u) { return __uint_as_float(u << 16); }
__device__ inline float bhi(unsigned int u) { return __uint_as_float(u & 0xffff0000u); }

__device__ inline unsigned short bf16rne(float f) {
    union { __hip_bfloat16 h; unsigned short u; } c;
    c.h = __float2bfloat16(f);
    return c.u;
}
__device__ inline unsigned int pk2(float a, float b) {
    return (unsigned int)bf16rne(a) | ((unsigned int)bf16rne(b) << 16);
}

// ---------------------------------------------------------------------------
// MFMA GEMM: [M,128](bf16 or fp32->bf16) @ Wt[384,128]^T + bias -> split
// outputs: agg[M][192] = k|v bf16 (384 B rows, 3 cache lines) and
// qs[M][192] = q|s bf16. K=128 fully staged in LDS with XOR swizzle
// (byte ^ (row&7)<<4) applied write-side AND read-side (rule #21).
// AF32: A is fp32 [M][128] (512 B rows), converted during staging.
// ---------------------------------------------------------------------------
template<bool AF32>
__global__ __launch_bounds__(256) void gemm_mfma(
    const void* __restrict__ Ap, const unsigned short* __restrict__ Wt,
    const float* __restrict__ bias,
    unsigned short* __restrict__ aggb, unsigned short* __restrict__ qsb,
    int M)
{
    __shared__ char lds[65536];
    char* sA = lds;
    char* sB = lds + 32768;
    const int tid = threadIdx.x;
    const int r0 = blockIdx.x * 128;
    const int c0 = blockIdx.y * 128;
    const char* Wb = (const char*)Wt + (size_t)c0 * 256;

    // stage A tile (128 rows x 256 B bf16), clamped at M-1
    if (AF32) {
        const char* Asrc = (const char*)Ap;          // 512 B fp32 rows
        #pragma unroll
        for (int sct = 0; sct < 8; ++sct) {
            int o = (sct * 256 + tid) * 16;          // bf16-tile byte offset
            int r = o >> 8;
            int gr = r0 + r; if (gr > M - 1) gr = M - 1;
            const char* p = Asrc + (size_t)gr * 512 + (o & 255) * 2;
            float4 a = *reinterpret_cast<const float4*>(p);
            float4 b = *reinterpret_cast<const float4*>(p + 16);
            uint4 val;
            val.x = pk2(a.x, a.y); val.y = pk2(a.z, a.w);
            val.z = pk2(b.x, b.y); val.w = pk2(b.z, b.w);
            *reinterpret_cast<uint4*>(sA + (o ^ ((r & 7) << 4))) = val;
        }
    } else {
        const char* Asrc = (const char*)Ap;          // 256 B bf16 rows
        #pragma unroll
        for (int sct = 0; sct < 8; ++sct) {
            int o = (sct * 256 + tid) * 16;
            int r = o >> 8;
            int gr = r0 + r; if (gr > M - 1) gr = M - 1;
            uint4 val = *reinterpret_cast<const uint4*>(Asrc + (size_t)gr * 256 + (o & 255));
            *reinterpret_cast<uint4*>(sA + (o ^ ((r & 7) << 4))) = val;
        }
    }
    // stage B tile (Wt rows c0..c0+127): contiguous 32 KB
    #pragma unroll
    for (int sct = 0; sct < 8; ++sct) {
        int o = (sct * 256 + tid) * 16;
        int r = o >> 8;
        uint4 val = *reinterpret_cast<const uint4*>(Wb + o);
        *reinterpret_cast<uint4*>(sB + (o ^ ((r & 7) << 4))) = val;
    }
    __syncthreads();

    const int lane = tid & 63, wid = tid >> 6;
    const int wm = wid >> 1, wn = wid & 1;
    const int qw = lane >> 4, c16 = lane & 15;

    f32x4 acc[4][4];
    #pragma unroll
    for (int a = 0; a < 4; ++a)
        #pragma unroll
        for (int b = 0; b < 4; ++b) acc[a][b] = (f32x4){0.f, 0.f, 0.f, 0.f};

    int aoff[4], boff[4];
    #pragma unroll
    for (int fm = 0; fm < 4; ++fm) {
        int r = wm * 64 + fm * 16 + c16;
        aoff[fm] = r * 256 + ((qw * 16) ^ ((r & 7) << 4));
    }
    #pragma unroll
    for (int fn = 0; fn < 4; ++fn) {
        int r = wn * 64 + fn * 16 + c16;
        boff[fn] = r * 256 + ((qw * 16) ^ ((r & 7) << 4));
    }

    #pragma unroll
    for (int ks = 0; ks < 4; ++ks) {
        const int kx = ks * 64;   // byte advance per k-step; XOR-safe (bits 6-7)
        bf16x8 af[4], bfr[4];
        #pragma unroll
        for (int fm = 0; fm < 4; ++fm)
            af[fm] = *reinterpret_cast<const bf16x8*>(sA + (aoff[fm] ^ kx));
        #pragma unroll
        for (int fn = 0; fn < 4; ++fn)
            bfr[fn] = *reinterpret_cast<const bf16x8*>(sB + (boff[fn] ^ kx));
        #pragma unroll
        for (int fm = 0; fm < 4; ++fm)
            #pragma unroll
            for (int fn = 0; fn < 4; ++fn)
                acc[fm][fn] = __builtin_amdgcn_mfma_f32_16x16x32_bf16(
                    af[fm], bfr[fn], acc[fm][fn], 0, 0, 0);
    }

    // epilogue: C/D layout col=lane&15, row=(lane>>4)*4+j. Each 16-col frag
    // tile lies in one 96-group (g wave-uniform). Route: g0->qs(q), g1/g2->
    // agg(k|v), g3->qs(s). Pair adjacent cols via shfl_xor(1).
    #pragma unroll
    for (int fn = 0; fn < 4; ++fn) {
        int colbase = c0 + wn * 64 + fn * 16;
        int g = colbase / 96;
        unsigned short* obuf; int elem0;
        if (g == 0)      { obuf = qsb;  elem0 = colbase; }
        else if (g == 3) { obuf = qsb;  elem0 = colbase - 192; }
        else             { obuf = aggb; elem0 = colbase - 96; }
        float bcol = bias[colbase + c16];
        #pragma unroll
        for (int fm = 0; fm < 4; ++fm) {
            #pragma unroll
            for (int j = 0; j < 4; ++j) {
                int rg = r0 + wm * 64 + fm * 16 + qw * 4 + j;
                float o = acc[fm][fn][j] + bcol;
                float o2 = __shfl_xor(o, 1);
                if (!(lane & 1) && rg < M) {
                    *reinterpret_cast<unsigned int*>(
                        (char*)obuf + (size_t)rg * 384 + (size_t)(elem0 + c16) * 2) = pk2(o, o2);
                }
            }
        }
    }
}

// ---------------------------------------------------------------------------
// Small fp32 GEMM for the head (N=32): 4x2 microtile, BM=64 BN=32 BK=32.
// ---------------------------------------------------------------------------
__global__ __launch_bounds__(256) void gemm_bias(
    const float* __restrict__ A, const float* __restrict__ W,
    const float* __restrict__ bias, float* __restrict__ C,
    int M, int N, int K)
{
    const int BM = 64, BN = 32, BK = 32;
    __shared__ float As[BK][BM];
    __shared__ float Ws[BK][BN];
    int tid = threadIdx.x;
    int tx = tid & 15;
    int ty = tid >> 4;
    int r0 = blockIdx.x * BM;
    int c0 = blockIdx.y * BN;
    float acc[4][2] = {};

    for (int kb = 0; kb < K; kb += BK) {
        #pragma unroll
        for (int t = 0; t < 2; ++t) {
            int slot = tid * 2 + t;
            int row  = slot >> 3;
            int kc   = (slot & 7) * 4;
            int gr = r0 + row; if (gr > M - 1) gr = M - 1;
            const float4 a = *reinterpret_cast<const float4*>(&A[(size_t)gr * K + kb + kc]);
            As[kc + 0][row] = a.x; As[kc + 1][row] = a.y;
            As[kc + 2][row] = a.z; As[kc + 3][row] = a.w;
        }
        {
            int row = tid >> 3;
            int cc  = (tid & 7) * 4;
            *reinterpret_cast<float4*>(&Ws[row][cc]) =
                *reinterpret_cast<const float4*>(&W[(size_t)(kb + row) * N + c0 + cc]);
        }
        __syncthreads();
        #pragma unroll
        for (int kk = 0; kk < BK; ++kk) {
            float4 a = *reinterpret_cast<const float4*>(&As[kk][ty * 4]);
            float2 w = *reinterpret_cast<const float2*>(&Ws[kk][tx * 2]);
            acc[0][0] += a.x * w.x; acc[0][1] += a.x * w.y;
            acc[1][0] += a.y * w.x; acc[1][1] += a.y * w.y;
            acc[2][0] += a.z * w.x; acc[2][1] += a.z * w.y;
            acc[3][0] += a.w * w.x; acc[3][1] += a.w * w.y;
        }
        __syncthreads();
    }
    float2 b2 = *reinterpret_cast<const float2*>(&bias[c0 + tx * 2]);
    #pragma unroll
    for (int i = 0; i < 4; ++i) {
        int gr = r0 + ty * 4 + i;
        if (gr < M) {
            float2 o;
            o.x = acc[i][0] + b2.x;
            o.y = acc[i][1] + b2.y;
            *reinterpret_cast<float2*>(&C[(size_t)gr * N + c0 + tx * 2]) = o;
        }
    }
}

// ---------------------------------------------------------------------------
// Pack weights transposed + bf16: Wt[384][128]; Wt[n][k] = Wg[k][n%96] (0 for
// k >= K). Also packs fp32 bias b4[384].
// ---------------------------------------------------------------------------
__global__ void pack_wt(const float* __restrict__ w0, const float* __restrict__ w1,
                        const float* __restrict__ w2, const float* __restrict__ w3,
                        const float* __restrict__ b0, const float* __restrict__ b1,
                        const float* __restrict__ b2, const float* __restrict__ b3,
                        unsigned short* __restrict__ Wt, float* __restrict__ b4, int K)
{
    int idx = blockIdx.x * blockDim.x + threadIdx.x;
    if (idx < 384 * 128) {
        int n = idx >> 7, k = idx & 127;
        int g = n / 96, c = n - g * 96;
        const float* w = (g == 0) ? w0 : (g == 1) ? w1 : (g == 2) ? w2 : w3;
        float v = (k < K) ? w[(size_t)k * 96 + c] : 0.f;
        Wt[idx] = bf16rne(v);
        if (k == 0) {
            const float* bb = (g == 0) ? b0 : (g == 1) ? b1 : (g == 2) ? b2 : b3;
            b4[n] = bb[c];
        }
    }
}

// ---------------------------------------------------------------------------
// CSR build: histogram -> parallel 3-kernel scan -> fill
// ---------------------------------------------------------------------------
__global__ void count_kernel(const int* __restrict__ dst, int* __restrict__ cnt, int E)
{
    int e = blockIdx.x * blockDim.x + threadIdx.x;
    if (e < E) atomicAdd(&cnt[dst[e]], 1);
}

__device__ inline int block_incl_scan(int v, int lane, int wid, int* ws)
{
    int x = v;
    #pragma unroll
    for (int off = 1; off < 64; off <<= 1) {
        int t = __shfl_up(x, off);
        if (lane >= off) x += t;
    }
    if (lane == 63) ws[wid] = x;
    __syncthreads();
    int woff = 0;
    #pragma unroll
    for (int w = 0; w < 4; ++w)
        if (w < wid) woff += ws[w];
    return woff + x;   // inclusive
}

__global__ __launch_bounds__(256) void scan_bsum(
    const int* __restrict__ cnt, int* __restrict__ bsum, int n)
{
    __shared__ int ws[4];
    int i = blockIdx.x * 256 + threadIdx.x;
    int v = (i < n) ? cnt[i] : 0;
    #pragma unroll
    for (int off = 32; off; off >>= 1) v += __shfl_xor(v, off);
    if ((threadIdx.x & 63) == 0) ws[threadIdx.x >> 6] = v;
    __syncthreads();
    if (threadIdx.x == 0) bsum[blockIdx.x] = ws[0] + ws[1] + ws[2] + ws[3];
}

__global__ __launch_bounds__(256) void scan_boff(
    int* __restrict__ bsum, int* __restrict__ rowN, int nb)
{
    __shared__ int ws[4];
    int tid = threadIdx.x;
    int v = (tid < nb) ? bsum[tid] : 0;
    int incl = block_incl_scan(v, tid & 63, tid >> 6, ws);
    if (tid < nb) bsum[tid] = incl - v;     // exclusive block offset
    if (tid == 255) *rowN = incl;           // grand total -> row[NN]
}

__global__ __launch_bounds__(256) void scan_final(
    const int* __restrict__ cnt, const int* __restrict__ boff,
    int* __restrict__ row, int* __restrict__ cursor, int n)
{
    __shared__ int ws[4];
    int i = blockIdx.x * 256 + threadIdx.x;
    int v = (i < n) ? cnt[i] : 0;
    int incl = block_incl_scan(v, threadIdx.x & 63, threadIdx.x >> 6, ws);
    if (i < n) {
        int e = boff[blockIdx.x] + incl - v;
        row[i] = e;
        cursor[i] = e;
    }
}

__global__ void fill_kernel(const int* __restrict__ src, const int* __restrict__ dst,
                            int* __restrict__ cursor, int* __restrict__ csr_src, int E)
{
    int e = blockIdx.x * blockDim.x + threadIdx.x;
    if (e < E) {
        int d = dst[e];
        int p = atomicAdd(&cursor[d], 1);
        csr_src[p] = src[e];
    }
}

// ---------------------------------------------------------------------------
// Fused attention aggregate. agg[n][192] = k|v bf16 (384 B rows = 3 cache
// lines/edge), qs[n][192] = q|s bf16. Half-wave (32 lanes) per edge, 8-edge
// unrolled main loop (4 independent shuffle chains). Lane c: dword = dims
// {2c,2c+1}; lanes 0-15 carry k dims 64-95, lanes 16-31 v dims 64-95 (xb).
// Max-free softmax -> fully reassociable accumulators.
// MODE 0: relu + bf16[128] zero-padded out. MODE 1: f32[96] out.
// ---------------------------------------------------------------------------
template<int MODE>
__global__ __launch_bounds__(256) void aggregate_kernel(
    const unsigned short* __restrict__ aggb, const unsigned short* __restrict__ qsb,
    const int* __restrict__ row, const int* __restrict__ csr,
    void* __restrict__ outv, int nnodes)
{
    const int wid  = threadIdx.x >> 6;
    const int lane = threadIdx.x & 63;
    const int c = lane & 31;
    const int h = lane >> 5;
    const int n = blockIdx.x * 4 + wid;
    if (n >= nnodes) return;
    const float scale = 0.10206207261596577f;   // 1/sqrt(96)
    const char* AG = (const char*)aggb;
    const char* QS = (const char*)qsb;
    const size_t qrb = (size_t)n * 384;

    const unsigned int qa  = *(const unsigned int*)(QS + qrb + 4 * c);
    const unsigned int qbu = *(const unsigned int*)(QS + qrb + 128 + 4 * (c & 15));
    const float qalo = blo(qa), qahi = bhi(qa);
    float qblo, qbhi;
    if (c < 16) { qblo = blo(qbu); qbhi = bhi(qbu); } else { qblo = 0.f; qbhi = 0.f; }
    const int xsel = (c < 16) ? 128 : 256;   // k dims 64-95 | v dims 64-95

    float s = 0.f, alo = 0.f, ahi = 0.f, xlo = 0.f, xhi = 0.f;
    const int beg = row[n], end = row[n + 1];

    auto do_pair = [&](int i0) {
        const int s0 = csr[i0 + h], s1 = csr[i0 + 2 + h];
        const size_t b0 = (size_t)s0 * 384, b1 = (size_t)s1 * 384;
        unsigned int ka0 = *(const unsigned int*)(AG + b0 + 4 * c);
        unsigned int xb0 = *(const unsigned int*)(AG + b0 + xsel + 4 * c);
        unsigned int va0 = *(const unsigned int*)(AG + b0 + 192 + 4 * c);
        unsigned int ka1 = *(const unsigned int*)(AG + b1 + 4 * c);
        unsigned int xb1 = *(const unsigned int*)(AG + b1 + xsel + 4 * c);
        unsigned int va1 = *(const unsigned int*)(AG + b1 + 192 + 4 * c);
        float p0 = qalo * blo(ka0) + qahi * bhi(ka0) + qblo * blo(xb0) + qbhi * bhi(xb0);
        float p1 = qalo * blo(ka1) + qahi * bhi(ka1) + qblo * blo(xb1) + qbhi * bhi(xb1);
        #pragma unroll
        for (int off = 1; off < 32; off <<= 1) {
            p0 += __shfl_xor(p0, off);
            p1 += __shfl_xor(p1, off);
        }
        float e0 = __expf(p0 * scale);
        float e1 = __expf(p1 * scale);
        float eb0 = (c >= 16) ? e0 : 0.f;
        float eb1 = (c >= 16) ? e1 : 0.f;
        s   += e0 + e1;
        alo += e0 * blo(va0) + e1 * blo(va1);
        ahi += e0 * bhi(va0) + e1 * bhi(va1);
        xlo += eb0 * blo(xb0) + eb1 * blo(xb1);
        xhi += eb0 * bhi(xb0) + eb1 * bhi(xb1);
    };

    int i = beg;
    for (; i + 8 <= end; i += 8) { do_pair(i); do_pair(i + 4); }
    for (; i + 4 <= end; i += 4) do_pair(i);
    for (; i < end; i += 2) {
        const int j = i + h;
        const int jc = (j < end) ? j : (end - 1);
        const int sc = csr[jc];
        const size_t b = (size_t)sc * 384;
        unsigned int ka = *(const unsigned int*)(AG + b + 4 * c);
        unsigned int xb = *(const unsigned int*)(AG + b + xsel + 4 * c);
        unsigned int va = *(const unsigned int*)(AG + b + 192 + 4 * c);
        float p = qalo * blo(ka) + qahi * bhi(ka) + qblo * blo(xb) + qbhi * bhi(xb);
        #pragma unroll
        for (int off = 1; off < 32; off <<= 1) p += __shfl_xor(p, off);
        float e = (j < end) ? __expf(p * scale) : 0.f;
        float eb = (c >= 16) ? e : 0.f;
        s += e;
        alo += e * blo(va); ahi += e * bhi(va);
        xlo += eb * blo(xb); xhi += eb * bhi(xb);
    }
    s   += __shfl_xor(s, 32);
    alo += __shfl_xor(alo, 32);
    ahi += __shfl_xor(ahi, 32);
    xlo += __shfl_xor(xlo, 32);
    xhi += __shfl_xor(xhi, 32);
    const float inv = 1.0f / (s + 1e-16f);

    if (lane < 32) {
        const unsigned int sa = *(const unsigned int*)(QS + qrb + 192 + 4 * c);
        float o0 = alo * inv + blo(sa);
        float o1 = ahi * inv + bhi(sa);
        if (MODE == 0) {
            o0 = fmaxf(o0, 0.f); o1 = fmaxf(o1, 0.f);
            char* O = (char*)outv;
            const size_t ob = (size_t)n * 256;
            *(unsigned int*)(O + ob + 4 * c) = pk2(o0, o1);
            if (c >= 16) {
                const unsigned int sx = *(const unsigned int*)(QS + qrb + 256 + 4 * c);
                float ox0 = fmaxf(xlo * inv + blo(sx), 0.f);
                float ox1 = fmaxf(xhi * inv + bhi(sx), 0.f);
                *(unsigned int*)(O + ob + 64 + 4 * c) = pk2(ox0, ox1);
            } else {
                *(unsigned int*)(O + ob + 192 + 4 * c) = 0u;   // zero-pad dims 96-127
            }
        } else {
            char* O = (char*)outv;
            const size_t ob = (size_t)n * 384;
            *(float2*)(O + ob + 8 * c) = make_float2(o0, o1);
            if (c >= 16) {
                const unsigned int sx = *(const unsigned int*)(QS + qrb + 256 + 4 * c);
                float ox0 = xlo * inv + blo(sx);
                float ox1 = xhi * inv + bhi(sx);
                *(float2*)(O + ob + 128 + 8 * c) = make_float2(ox0, ox1);
            }
        }
    }
}

// ---------------------------------------------------------------------------
extern "C" void kernel_launch(void* const* d_in, const int* in_sizes, int n_in,
                              void* d_out, int out_size, void* d_ws, size_t ws_size,
                              hipStream_t stream)
{
    const int NN = N_NODES_C, NE = N_EDGES_C;
    const float* x  = (const float*)d_in[0];
    const int*   ei = (const int*)d_in[1];
    const int* src = ei;
    const int* dst = ei + NE;

    const float* Wq1 = (const float*)d_in[2];  const float* bq1 = (const float*)d_in[3];
    const float* Wk1 = (const float*)d_in[4];  const float* bk1 = (const float*)d_in[5];
    const float* Wv1 = (const float*)d_in[6];  const float* bv1 = (const float*)d_in[7];
    const float* Ws1 = (const float*)d_in[8];  const float* bs1 = (const float*)d_in[9];
    const float* Wq2 = (const float*)d_in[10]; const float* bq2 = (const float*)d_in[11];
    const float* Wk2 = (const float*)d_in[12]; const float* bk2 = (const float*)d_in[13];
    const float* Wv2 = (const float*)d_in[14]; const float* bv2 = (const float*)d_in[15];
    const float* Ws2 = (const float*)d_in[16]; const float* bs2 = (const float*)d_in[17];
    const float* Wd  = (const float*)d_in[18]; const float* bd  = (const float*)d_in[19];

    // byte-addressed workspace carve-up (256-B aligned chunks)
    char* base = (char*)d_ws;
    size_t off = 0;
    auto alloc = [&](size_t bytes) -> void* {
        void* p = base + off;
        off += (bytes + 255) & ~(size_t)255;
        return p;
    };
    unsigned short* aggb   = (unsigned short*)alloc((size_t)NN * 192 * 2);  // k|v
    unsigned short* qsb    = (unsigned short*)alloc((size_t)NN * 192 * 2);  // q|s
    unsigned short* hb16   = (unsigned short*)alloc((size_t)NN * 128 * 2);
    float*          h2f    = (float*)alloc((size_t)NN * 96 * 4);
    unsigned short* Wt4a   = (unsigned short*)alloc(384 * 128 * 2);
    unsigned short* Wt4b   = (unsigned short*)alloc(384 * 128 * 2);
    float*          b4a    = (float*)alloc(384 * 4);
    float*          b4b    = (float*)alloc(384 * 4);
    int*            rowp   = (int*)alloc((NN + 1) * 4);
    int*            cursor = (int*)alloc(NN * 4);
    int*            bsum   = (int*)alloc(256 * 4);
    int*            csr    = (int*)alloc((size_t)NE * 4);

    const int NB = (NN + 255) / 256;   // 196 scan blocks

    // ---- weight packing
    pack_wt<<<192, 256, 0, stream>>>(Wq1, Wk1, Wv1, Ws1, bq1, bk1, bv1, bs1, Wt4a, b4a, 128);
    pack_wt<<<192, 256, 0, stream>>>(Wq2, Wk2, Wv2, Ws2, bq2, bk2, bv2, bs2, Wt4b, b4b, 96);

    // ---- CSR build (parallel scan)
    hipMemsetAsync(cursor, 0, NN * sizeof(int), stream);
    count_kernel<<<(NE + 255) / 256, 256, 0, stream>>>(dst, cursor, NE);
    scan_bsum<<<NB, 256, 0, stream>>>(cursor, bsum, NN);
    scan_boff<<<1, 256, 0, stream>>>(bsum, &rowp[NN], NB);
    scan_final<<<NB, 256, 0, stream>>>(cursor, bsum, rowp, cursor, NN);
    fill_kernel<<<(NE + 255) / 256, 256, 0, stream>>>(src, dst, cursor, csr, NE);

    dim3 blk(256);
    dim3 gg((NN + 127) / 128, 3);
    int aggGrid = (NN + 3) / 4;

    // ---- layer 1 (A = fp32 x, converted during staging)
    gemm_mfma<true><<<gg, blk, 0, stream>>>(x, Wt4a, b4a, aggb, qsb, NN);
    aggregate_kernel<0><<<aggGrid, blk, 0, stream>>>(aggb, qsb, rowp, csr, hb16, NN);

    // ---- layer 2 (A = bf16 hb16, K zero-padded 96->128)
    gemm_mfma<false><<<gg, blk, 0, stream>>>(hb16, Wt4b, b4b, aggb, qsb, NN);
    aggregate_kernel<1><<<aggGrid, blk, 0, stream>>>(aggb, qsb, rowp, csr, h2f, NN);

    // ---- head (fp32): d_out = h2f @ Wd + bd
    dim3 g32((NN + 63) / 64, 1);
    gemm_bias<<<g32, blk, 0, stream>>>(h2f, Wd, bd, (float*)d_out, NN, 32, 96);
}

// Round 6
// 304.074 us; speedup vs baseline: 2.4881x; 1.1544x over previous
//
#include <hip/hip_runtime.h>
#include <hip/hip_bf16.h>
#include <math.h>

#define NN_C 50000
#define NE_C 800000
#define NBKT 196          // ceil(NN/256) coarse buckets (256 dst nodes each)
#define E_PER_BLK 4096
#define S1_BLOCKS 196     // ceil(NE/4096)
#define S2_CAP 8192       // bucket capacity (mean 4096, sigma ~64)

typedef short bf16x8 __attribute__((ext_vector_type(8)));
typedef float f32x4 __attribute__((ext_vector_type(4)));

__device__ inline float blo(unsigned int u) { return __uint_as_float(u << 16); }
__device__ inline float bhi(unsigned int u) { return __uint_as_float(u & 0xffff0000u); }

__device__ inline unsigned short bf16rne(float f) {
    union { __hip_bfloat16 h; unsigned short u; } c;
    c.h = __float2bfloat16(f);
    return c.u;
}
__device__ inline unsigned int pk2(float a, float b) {
    return (unsigned int)bf16rne(a) | ((unsigned int)bf16rne(b) << 16);
}

__device__ inline int block_incl_scan(int v, int lane, int wid, int* ws)
{
    int x = v;
    #pragma unroll
    for (int off = 1; off < 64; off <<= 1) {
        int t = __shfl_up(x, off);
        if (lane >= off) x += t;
    }
    if (lane == 63) ws[wid] = x;
    __syncthreads();
    int woff = 0;
    #pragma unroll
    for (int w = 0; w < 4; ++w)
        if (w < wid) woff += ws[w];
    return woff + x;   // inclusive
}

// ---------------------------------------------------------------------------
// MFMA GEMM: [M,128](bf16 or fp32->bf16) @ Wt[384,128]^T + bias -> split
// outputs agg[M][192]=k|v bf16, qs[M][192]=q|s bf16. K=128 in LDS, XOR
// swizzle (byte ^ (row&7)<<4) write-side AND read-side.
// ---------------------------------------------------------------------------
template<bool AF32>
__global__ __launch_bounds__(256) void gemm_mfma(
    const void* __restrict__ Ap, const unsigned short* __restrict__ Wt,
    const float* __restrict__ bias,
    unsigned short* __restrict__ aggb, unsigned short* __restrict__ qsb,
    int M)
{
    __shared__ char lds[65536];
    char* sA = lds;
    char* sB = lds + 32768;
    const int tid = threadIdx.x;
    const int r0 = blockIdx.x * 128;
    const int c0 = blockIdx.y * 128;
    const char* Wb = (const char*)Wt + (size_t)c0 * 256;

    if (AF32) {
        const char* Asrc = (const char*)Ap;          // 512 B fp32 rows
        #pragma unroll
        for (int sct = 0; sct < 8; ++sct) {
            int o = (sct * 256 + tid) * 16;
            int r = o >> 8;
            int gr = r0 + r; if (gr > M - 1) gr = M - 1;
            const char* p = Asrc + (size_t)gr * 512 + (o & 255) * 2;
            float4 a = *reinterpret_cast<const float4*>(p);
            float4 b = *reinterpret_cast<const float4*>(p + 16);
            uint4 val;
            val.x = pk2(a.x, a.y); val.y = pk2(a.z, a.w);
            val.z = pk2(b.x, b.y); val.w = pk2(b.z, b.w);
            *reinterpret_cast<uint4*>(sA + (o ^ ((r & 7) << 4))) = val;
        }
    } else {
        const char* Asrc = (const char*)Ap;          // 256 B bf16 rows
        #pragma unroll
        for (int sct = 0; sct < 8; ++sct) {
            int o = (sct * 256 + tid) * 16;
            int r = o >> 8;
            int gr = r0 + r; if (gr > M - 1) gr = M - 1;
            uint4 val = *reinterpret_cast<const uint4*>(Asrc + (size_t)gr * 256 + (o & 255));
            *reinterpret_cast<uint4*>(sA + (o ^ ((r & 7) << 4))) = val;
        }
    }
    #pragma unroll
    for (int sct = 0; sct < 8; ++sct) {
        int o = (sct * 256 + tid) * 16;
        int r = o >> 8;
        uint4 val = *reinterpret_cast<const uint4*>(Wb + o);
        *reinterpret_cast<uint4*>(sB + (o ^ ((r & 7) << 4))) = val;
    }
    __syncthreads();

    const int lane = tid & 63, wid = tid >> 6;
    const int wm = wid >> 1, wn = wid & 1;
    const int qw = lane >> 4, c16 = lane & 15;

    f32x4 acc[4][4];
    #pragma unroll
    for (int a = 0; a < 4; ++a)
        #pragma unroll
        for (int b = 0; b < 4; ++b) acc[a][b] = (f32x4){0.f, 0.f, 0.f, 0.f};

    int aoff[4], boff[4];
    #pragma unroll
    for (int fm = 0; fm < 4; ++fm) {
        int r = wm * 64 + fm * 16 + c16;
        aoff[fm] = r * 256 + ((qw * 16) ^ ((r & 7) << 4));
    }
    #pragma unroll
    for (int fn = 0; fn < 4; ++fn) {
        int r = wn * 64 + fn * 16 + c16;
        boff[fn] = r * 256 + ((qw * 16) ^ ((r & 7) << 4));
    }

    #pragma unroll
    for (int ks = 0; ks < 4; ++ks) {
        const int kx = ks * 64;
        bf16x8 af[4], bfr[4];
        #pragma unroll
        for (int fm = 0; fm < 4; ++fm)
            af[fm] = *reinterpret_cast<const bf16x8*>(sA + (aoff[fm] ^ kx));
        #pragma unroll
        for (int fn = 0; fn < 4; ++fn)
            bfr[fn] = *reinterpret_cast<const bf16x8*>(sB + (boff[fn] ^ kx));
        #pragma unroll
        for (int fm = 0; fm < 4; ++fm)
            #pragma unroll
            for (int fn = 0; fn < 4; ++fn)
                acc[fm][fn] = __builtin_amdgcn_mfma_f32_16x16x32_bf16(
                    af[fm], bfr[fn], acc[fm][fn], 0, 0, 0);
    }

    #pragma unroll
    for (int fn = 0; fn < 4; ++fn) {
        int colbase = c0 + wn * 64 + fn * 16;
        int g = colbase / 96;
        unsigned short* obuf; int elem0;
        if (g == 0)      { obuf = qsb;  elem0 = colbase; }
        else if (g == 3) { obuf = qsb;  elem0 = colbase - 192; }
        else             { obuf = aggb; elem0 = colbase - 96; }
        float bcol = bias[colbase + c16];
        #pragma unroll
        for (int fm = 0; fm < 4; ++fm) {
            #pragma unroll
            for (int j = 0; j < 4; ++j) {
                int rg = r0 + wm * 64 + fm * 16 + qw * 4 + j;
                float o = acc[fm][fn][j] + bcol;
                float o2 = __shfl_xor(o, 1);
                if (!(lane & 1) && rg < M) {
                    *reinterpret_cast<unsigned int*>(
                        (char*)obuf + (size_t)rg * 384 + (size_t)(elem0 + c16) * 2) = pk2(o, o2);
                }
            }
        }
    }
}

// ---------------------------------------------------------------------------
// Setup: blocks 0-191 pack layer-1 weights, 192-383 layer-2, 384+ histogram
// of dst into NBKT coarse buckets (LDS-aggregated).
// ---------------------------------------------------------------------------
__global__ __launch_bounds__(256) void setup_kernel(
    const float* __restrict__ w0a, const float* __restrict__ w1a,
    const float* __restrict__ w2a, const float* __restrict__ w3a,
    const float* __restrict__ b0a, const float* __restrict__ b1a,
    const float* __restrict__ b2a, const float* __restrict__ b3a,
    const float* __restrict__ w0b, const float* __restrict__ w1b,
    const float* __restrict__ w2b, const float* __restrict__ w3b,
    const float* __restrict__ b0b, const float* __restrict__ b1b,
    const float* __restrict__ b2b, const float* __restrict__ b3b,
    const int* __restrict__ dst,
    unsigned short* __restrict__ WtA, float* __restrict__ b4a,
    unsigned short* __restrict__ WtB, float* __restrict__ b4b,
    int* __restrict__ bucketCnt)
{
    __shared__ int hist[NBKT];
    const int tid = threadIdx.x;
    const int blk = blockIdx.x;
    if (blk < 384) {
        const bool L2w = blk >= 192;
        int idx = (L2w ? blk - 192 : blk) * 256 + tid;   // < 384*128
        int n = idx >> 7, k = idx & 127;
        int g = n / 96, c = n - g * 96;
        const float* w; const float* bb;
        if (!L2w) {
            w = (g == 0) ? w0a : (g == 1) ? w1a : (g == 2) ? w2a : w3a;
            bb = (g == 0) ? b0a : (g == 1) ? b1a : (g == 2) ? b2a : b3a;
            WtA[idx] = bf16rne((k < 128) ? w[(size_t)k * 96 + c] : 0.f);
            if (k == 0) b4a[n] = bb[c];
        } else {
            w = (g == 0) ? w0b : (g == 1) ? w1b : (g == 2) ? w2b : w3b;
            bb = (g == 0) ? b0b : (g == 1) ? b1b : (g == 2) ? b2b : b3b;
            WtB[idx] = bf16rne((k < 96) ? w[(size_t)k * 96 + c] : 0.f);
            if (k == 0) b4b[n] = bb[c];
        }
    } else {
        const int hb = blk - 384;
        for (int t = tid; t < NBKT; t += 256) hist[t] = 0;
        __syncthreads();
        const int e0 = hb * E_PER_BLK;
        const int ne = min(E_PER_BLK, NE_C - e0);
        for (int j = tid; j < ne; j += 256)
            atomicAdd(&hist[((unsigned)dst[e0 + j]) >> 8], 1);
        __syncthreads();
        for (int t = tid; t < NBKT; t += 256)
            if (hist[t]) atomicAdd(&bucketCnt[t], hist[t]);
    }
}

// ---------------------------------------------------------------------------
// 1-block scan of bucket counts -> bucketBase[NBKT+1], gCur init.
// ---------------------------------------------------------------------------
__global__ __launch_bounds__(256) void scanb_kernel(
    const int* __restrict__ bucketCnt, int* __restrict__ bucketBase,
    int* __restrict__ gCur)
{
    __shared__ int ws[4];
    const int tid = threadIdx.x;
    int v = (tid < NBKT) ? bucketCnt[tid] : 0;
    int incl = block_incl_scan(v, tid & 63, tid >> 6, ws);
    int excl = incl - v;
    if (tid < NBKT) { bucketBase[tid] = excl; gCur[tid] = excl; }
    if (tid == NBKT - 1) bucketBase[NBKT] = incl;
}

// ---------------------------------------------------------------------------
// Stage 1: bin edges into coarse buckets with LDS staging; per-bucket runs
// written coalesced to bktArr (packed (dst<<16)|src).
// ---------------------------------------------------------------------------
__global__ __launch_bounds__(256) void stage1_kernel(
    const int* __restrict__ src, const int* __restrict__ dst,
    int* __restrict__ gCur, unsigned int* __restrict__ bktArr)
{
    __shared__ int hist[NBKT], loff[NBKT], lcur[NBKT], gbase[NBKT];
    __shared__ unsigned int bufRaw[E_PER_BLK];
    __shared__ unsigned int buf[E_PER_BLK];
    __shared__ int ws[4];
    const int tid = threadIdx.x;
    const int e0 = blockIdx.x * E_PER_BLK;
    const int ne = min(E_PER_BLK, NE_C - e0);

    for (int t = tid; t < NBKT; t += 256) hist[t] = 0;
    __syncthreads();
    for (int j = tid; j < ne; j += 256) {
        int d = dst[e0 + j], s = src[e0 + j];
        unsigned int pk = ((unsigned)d << 16) | (unsigned)s;
        bufRaw[j] = pk;
        atomicAdd(&hist[(unsigned)d >> 8], 1);
    }
    __syncthreads();
    {
        int v = (tid < NBKT) ? hist[tid] : 0;
        int incl = block_incl_scan(v, tid & 63, tid >> 6, ws);
        if (tid < NBKT) { loff[tid] = incl - v; lcur[tid] = incl - v; }
    }
    __syncthreads();
    for (int j = tid; j < ne; j += 256) {
        unsigned int pk = bufRaw[j];
        int p = atomicAdd(&lcur[pk >> 24], 1);
        buf[p] = pk;
    }
    __syncthreads();
    if (tid < NBKT && hist[tid] > 0) gbase[tid] = atomicAdd(&gCur[tid], hist[tid]);
    __syncthreads();
    for (int j = tid; j < ne; j += 256) {
        unsigned int pk = buf[j];
        int b = pk >> 24;
        bktArr[gbase[b] + (j - loff[b])] = pk;
    }
}

// ---------------------------------------------------------------------------
// Stage 2: one block per bucket -> exact per-node CSR in LDS, coalesced
// writes of csr (src ints) and row offsets.
// ---------------------------------------------------------------------------
__global__ __launch_bounds__(256) void stage2_kernel(
    const unsigned int* __restrict__ bktArr, const int* __restrict__ bucketBase,
    int* __restrict__ csr, int* __restrict__ row)
{
    __shared__ int ncnt[256], noff[256], ncur[256];
    __shared__ int outb[S2_CAP];
    __shared__ int ws[4];
    const int tid = threadIdx.x;
    const int b = blockIdx.x;
    const int base = bucketBase[b];
    const int cnt = bucketBase[b + 1] - base;

    ncnt[tid] = 0;
    __syncthreads();
    for (int j = tid; j < cnt; j += 256)
        atomicAdd(&ncnt[(bktArr[base + j] >> 16) & 255], 1);
    __syncthreads();
    {
        int v = ncnt[tid];
        int incl = block_incl_scan(v, tid & 63, tid >> 6, ws);
        noff[tid] = incl - v; ncur[tid] = incl - v;
    }
    __syncthreads();
    for (int j = tid; j < cnt; j += 256) {
        unsigned int pk = bktArr[base + j];
        int p = atomicAdd(&ncur[(pk >> 16) & 255], 1);
        if (p < S2_CAP) outb[p] = (int)(pk & 0xFFFFu);
    }
    __syncthreads();
    for (int j = tid; j < cnt && j < S2_CAP; j += 256) csr[base + j] = outb[j];
    const int node0 = b * 256;
    if (node0 + tid < NN_C) row[node0 + tid] = base + noff[tid];
    if (b == 0 && tid == 0) row[NN_C] = NE_C;
}

// ---------------------------------------------------------------------------
// Fused attention aggregate. agg[n][192]=k|v bf16 (384B rows), qs[n][192]=q|s.
// Half-wave per edge, 8-edge unroll, max-free softmax.
// MODE 0: relu + bf16[128] zero-padded out (next layer's A).
// MODE 1: fused head -> d_out[n][32] f32 = (agg+skip) @ Wd + bd.
// Grid must satisfy grid*4 == nnodes exactly (no early return: barriers).
// ---------------------------------------------------------------------------
template<int MODE>
__global__ __launch_bounds__(256) void aggregate_kernel(
    const unsigned short* __restrict__ aggb, const unsigned short* __restrict__ qsb,
    const int* __restrict__ row, const int* __restrict__ csr,
    const float* __restrict__ Wd, const float* __restrict__ bd,
    void* __restrict__ outv, int nnodes)
{
    __shared__ float headL[MODE == 1 ? (96 * 32 + 32 + 4 * 96) : 1];
    const int tid  = threadIdx.x;
    const int wid  = tid >> 6;
    const int lane = tid & 63;
    const int c = lane & 31;
    const int h = lane >> 5;
    const int n = blockIdx.x * 4 + wid;

    if constexpr (MODE == 1) {
        for (int t = tid; t < 3072; t += 256) headL[t] = Wd[t];
        if (tid < 32) headL[3072 + tid] = bd[tid];
    }

    const float scale = 0.10206207261596577f;   // 1/sqrt(96)
    const char* AG = (const char*)aggb;
    const char* QS = (const char*)qsb;
    const size_t qrb = (size_t)n * 384;

    const unsigned int qa  = *(const unsigned int*)(QS + qrb + 4 * c);
    const unsigned int qbu = *(const unsigned int*)(QS + qrb + 128 + 4 * (c & 15));
    const float qalo = blo(qa), qahi = bhi(qa);
    float qblo, qbhi;
    if (c < 16) { qblo = blo(qbu); qbhi = bhi(qbu); } else { qblo = 0.f; qbhi = 0.f; }
    const int xsel = (c < 16) ? 128 : 256;   // k dims 64-95 | v dims 64-95

    float s = 0.f, alo = 0.f, ahi = 0.f, xlo = 0.f, xhi = 0.f;
    const int beg = row[n], end = row[n + 1];

    auto do_pair = [&](int i0) {
        const int s0 = csr[i0 + h], s1 = csr[i0 + 2 + h];
        const size_t b0 = (size_t)s0 * 384, b1 = (size_t)s1 * 384;
        unsigned int ka0 = *(const unsigned int*)(AG + b0 + 4 * c);
        unsigned int xb0 = *(const unsigned int*)(AG + b0 + xsel + 4 * c);
        unsigned int va0 = *(const unsigned int*)(AG + b0 + 192 + 4 * c);
        unsigned int ka1 = *(const unsigned int*)(AG + b1 + 4 * c);
        unsigned int xb1 = *(const unsigned int*)(AG + b1 + xsel + 4 * c);
        unsigned int va1 = *(const unsigned int*)(AG + b1 + 192 + 4 * c);
        float p0 = qalo * blo(ka0) + qahi * bhi(ka0) + qblo * blo(xb0) + qbhi * bhi(xb0);
        float p1 = qalo * blo(ka1) + qahi * bhi(ka1) + qblo * blo(xb1) + qbhi * bhi(xb1);
        #pragma unroll
        for (int off = 1; off < 32; off <<= 1) {
            p0 += __shfl_xor(p0, off);
            p1 += __shfl_xor(p1, off);
        }
        float e0 = __expf(p0 * scale);
        float e1 = __expf(p1 * scale);
        float eb0 = (c >= 16) ? e0 : 0.f;
        float eb1 = (c >= 16) ? e1 : 0.f;
        s   += e0 + e1;
        alo += e0 * blo(va0) + e1 * blo(va1);
        ahi += e0 * bhi(va0) + e1 * bhi(va1);
        xlo += eb0 * blo(xb0) + eb1 * blo(xb1);
        xhi += eb0 * bhi(xb0) + eb1 * bhi(xb1);
    };

    int i = beg;
    for (; i + 8 <= end; i += 8) { do_pair(i); do_pair(i + 4); }
    for (; i + 4 <= end; i += 4) do_pair(i);
    for (; i < end; i += 2) {
        const int j = i + h;
        const int jc = (j < end) ? j : (end - 1);
        const int sc = csr[jc];
        const size_t b = (size_t)sc * 384;
        unsigned int ka = *(const unsigned int*)(AG + b + 4 * c);
        unsigned int xb = *(const unsigned int*)(AG + b + xsel + 4 * c);
        unsigned int va = *(const unsigned int*)(AG + b + 192 + 4 * c);
        float p = qalo * blo(ka) + qahi * bhi(ka) + qblo * blo(xb) + qbhi * bhi(xb);
        #pragma unroll
        for (int off = 1; off < 32; off <<= 1) p += __shfl_xor(p, off);
        float e = (j < end) ? __expf(p * scale) : 0.f;
        float eb = (c >= 16) ? e : 0.f;
        s += e;
        alo += e * blo(va); ahi += e * bhi(va);
        xlo += eb * blo(xb); xhi += eb * bhi(xb);
    }
    s   += __shfl_xor(s, 32);
    alo += __shfl_xor(alo, 32);
    ahi += __shfl_xor(ahi, 32);
    xlo += __shfl_xor(xlo, 32);
    xhi += __shfl_xor(xhi, 32);
    const float inv = 1.0f / (s + 1e-16f);

    if constexpr (MODE == 0) {
        if (lane < 32) {
            const unsigned int sa = *(const unsigned int*)(QS + qrb + 192 + 4 * c);
            float o0 = fmaxf(alo * inv + blo(sa), 0.f);
            float o1 = fmaxf(ahi * inv + bhi(sa), 0.f);
            char* O = (char*)outv;
            const size_t ob = (size_t)n * 256;
            *(unsigned int*)(O + ob + 4 * c) = pk2(o0, o1);
            if (c >= 16) {
                const unsigned int sx = *(const unsigned int*)(QS + qrb + 256 + 4 * c);
                float ox0 = fmaxf(xlo * inv + blo(sx), 0.f);
                float ox1 = fmaxf(xhi * inv + bhi(sx), 0.f);
                *(unsigned int*)(O + ob + 64 + 4 * c) = pk2(ox0, ox1);
            } else {
                *(unsigned int*)(O + ob + 192 + 4 * c) = 0u;
            }
        }
    } else {
        // stage o[96] to LDS, then fused head GEMV: out = o @ Wd + bd
        float* oW = headL + 3104 + wid * 96;
        if (lane < 32) {
            const unsigned int sa = *(const unsigned int*)(QS + qrb + 192 + 4 * c);
            oW[2 * c]     = alo * inv + blo(sa);
            oW[2 * c + 1] = ahi * inv + bhi(sa);
            if (c >= 16) {
                const unsigned int sx = *(const unsigned int*)(QS + qrb + 256 + 4 * c);
                oW[2 * c + 32] = xlo * inv + blo(sx);
                oW[2 * c + 33] = xhi * inv + bhi(sx);
            }
        }
        __syncthreads();
        float acc = 0.f;
        const int d0 = h * 48;
        #pragma unroll
        for (int d = 0; d < 48; ++d)
            acc += oW[d0 + d] * headL[(d0 + d) * 32 + c];
        acc += __shfl_xor(acc, 32);
        if (lane < 32)
            ((float*)outv)[(size_t)n * 32 + c] = acc + headL[3072 + c];
    }
}

// ---------------------------------------------------------------------------
extern "C" void kernel_launch(void* const* d_in, const int* in_sizes, int n_in,
                              void* d_out, int out_size, void* d_ws, size_t ws_size,
                              hipStream_t stream)
{
    const int NN = NN_C, NE = NE_C;
    const float* x  = (const float*)d_in[0];
    const int*   ei = (const int*)d_in[1];
    const int* src = ei;
    const int* dst = ei + NE;

    const float* Wq1 = (const float*)d_in[2];  const float* bq1 = (const float*)d_in[3];
    const float* Wk1 = (const float*)d_in[4];  const float* bk1 = (const float*)d_in[5];
    const float* Wv1 = (const float*)d_in[6];  const float* bv1 = (const float*)d_in[7];
    const float* Ws1 = (const float*)d_in[8];  const float* bs1 = (const float*)d_in[9];
    const float* Wq2 = (const float*)d_in[10]; const float* bq2 = (const float*)d_in[11];
    const float* Wk2 = (const float*)d_in[12]; const float* bk2 = (const float*)d_in[13];
    const float* Wv2 = (const float*)d_in[14]; const float* bv2 = (const float*)d_in[15];
    const float* Ws2 = (const float*)d_in[16]; const float* bs2 = (const float*)d_in[17];
    const float* Wd  = (const float*)d_in[18]; const float* bd  = (const float*)d_in[19];

    char* base = (char*)d_ws;
    size_t off = 0;
    auto alloc = [&](size_t bytes) -> void* {
        void* p = base + off;
        off += (bytes + 255) & ~(size_t)255;
        return p;
    };
    unsigned short* aggb   = (unsigned short*)alloc((size_t)NN * 192 * 2);  // k|v
    unsigned short* qsb    = (unsigned short*)alloc((size_t)NN * 192 * 2);  // q|s
    unsigned short* hb16   = (unsigned short*)alloc((size_t)NN * 128 * 2);
    unsigned short* Wt4a   = (unsigned short*)alloc(384 * 128 * 2);
    unsigned short* Wt4b   = (unsigned short*)alloc(384 * 128 * 2);
    float*          b4a    = (float*)alloc(384 * 4);
    float*          b4b    = (float*)alloc(384 * 4);
    int*            bucketCnt  = (int*)alloc(NBKT * 4);
    int*            bucketBase = (int*)alloc((NBKT + 1) * 4);
    int*            gCur   = (int*)alloc(NBKT * 4);
    unsigned int*   bktArr = (unsigned int*)alloc((size_t)NE * 4);
    int*            csr    = (int*)alloc((size_t)NE * 4);
    int*            rowp   = (int*)alloc((NN + 1) * 4);

    // ---- CSR build + weight packing (fused)
    hipMemsetAsync(bucketCnt, 0, NBKT * sizeof(int), stream);
    setup_kernel<<<384 + S1_BLOCKS, 256, 0, stream>>>(
        Wq1, Wk1, Wv1, Ws1, bq1, bk1, bv1, bs1,
        Wq2, Wk2, Wv2, Ws2, bq2, bk2, bv2, bs2,
        dst, Wt4a, b4a, Wt4b, b4b, bucketCnt);
    scanb_kernel<<<1, 256, 0, stream>>>(bucketCnt, bucketBase, gCur);
    stage1_kernel<<<S1_BLOCKS, 256, 0, stream>>>(src, dst, gCur, bktArr);
    stage2_kernel<<<NBKT, 256, 0, stream>>>(bktArr, bucketBase, csr, rowp);

    dim3 blk(256);
    dim3 gg((NN + 127) / 128, 3);
    const int aggGrid = NN / 4;   // exact: 50000 = 12500*4 (no early return)

    // ---- layer 1 (A = fp32 x, converted during staging)
    gemm_mfma<true><<<gg, blk, 0, stream>>>(x, Wt4a, b4a, aggb, qsb, NN);
    aggregate_kernel<0><<<aggGrid, blk, 0, stream>>>(
        aggb, qsb, rowp, csr, nullptr, nullptr, hb16, NN);

    // ---- layer 2 (A = bf16, K zero-padded 96->128) + fused head -> d_out
    gemm_mfma<false><<<gg, blk, 0, stream>>>(hb16, Wt4b, b4b, aggb, qsb, NN);
    aggregate_kernel<1><<<aggGrid, blk, 0, stream>>>(
        aggb, qsb, rowp, csr, Wd, bd, d_out, NN);
}

// Round 8
// 285.260 us; speedup vs baseline: 2.6522x; 1.0660x over previous
//
#include <hip/hip_runtime.h>
#include <hip/hip_bf16.h>
#include <math.h>

#define NN_C 50000
#define NE_C 800000
#define NBKT 196          // ceil(NN/256) coarse buckets (256 dst nodes each)
#define E_PER_BLK 4096
#define S1_BLOCKS 196     // ceil(NE/4096)
#define S2_CAP 8192       // bucket capacity (mean 4096, sigma ~64)

typedef short bf16x8 __attribute__((ext_vector_type(8)));
typedef float f32x4 __attribute__((ext_vector_type(4)));

struct U3 { unsigned int x, y, z; };   // 12 B, 4-B aligned

__device__ inline float blo(unsigned int u) { return __uint_as_float(u << 16); }
__device__ inline float bhi(unsigned int u) { return __uint_as_float(u & 0xffff0000u); }

__device__ inline unsigned short bf16rne(float f) {
    union { __hip_bfloat16 h; unsigned short u; } c;
    c.h = __float2bfloat16(f);
    return c.u;
}
__device__ inline unsigned int pk2(float a, float b) {
    return (unsigned int)bf16rne(a) | ((unsigned int)bf16rne(b) << 16);
}

__device__ inline int block_incl_scan(int v, int lane, int wid, int* ws)
{
    int x = v;
    #pragma unroll
    for (int off = 1; off < 64; off <<= 1) {
        int t = __shfl_up(x, off);
        if (lane >= off) x += t;
    }
    if (lane == 63) ws[wid] = x;
    __syncthreads();
    int woff = 0;
    #pragma unroll
    for (int w = 0; w < 4; ++w)
        if (w < wid) woff += ws[w];
    return woff + x;   // inclusive
}

// ---------------------------------------------------------------------------
// MFMA GEMM: [M,128](bf16 or fp32->bf16) @ Wt[384,128]^T + bias -> split
// outputs agg[M][192]=k|v bf16, qs[M][192]=q|s bf16. K=128 in LDS, XOR
// swizzle (byte ^ (row&7)<<4) write-side AND read-side.
// ---------------------------------------------------------------------------
template<bool AF32>
__global__ __launch_bounds__(256) void gemm_mfma(
    const void* __restrict__ Ap, const unsigned short* __restrict__ Wt,
    const float* __restrict__ bias,
    unsigned short* __restrict__ aggb, unsigned short* __restrict__ qsb,
    int M)
{
    __shared__ char lds[65536];
    char* sA = lds;
    char* sB = lds + 32768;
    const int tid = threadIdx.x;
    const int r0 = blockIdx.x * 128;
    const int c0 = blockIdx.y * 128;
    const char* Wb = (const char*)Wt + (size_t)c0 * 256;

    if (AF32) {
        const char* Asrc = (const char*)Ap;          // 512 B fp32 rows
        #pragma unroll
        for (int sct = 0; sct < 8; ++sct) {
            int o = (sct * 256 + tid) * 16;
            int r = o >> 8;
            int gr = r0 + r; if (gr > M - 1) gr = M - 1;
            const char* p = Asrc + (size_t)gr * 512 + (o & 255) * 2;
            float4 a = *reinterpret_cast<const float4*>(p);
            float4 b = *reinterpret_cast<const float4*>(p + 16);
            uint4 val;
            val.x = pk2(a.x, a.y); val.y = pk2(a.z, a.w);
            val.z = pk2(b.x, b.y); val.w = pk2(b.z, b.w);
            *reinterpret_cast<uint4*>(sA + (o ^ ((r & 7) << 4))) = val;
        }
    } else {
        const char* Asrc = (const char*)Ap;          // 256 B bf16 rows
        #pragma unroll
        for (int sct = 0; sct < 8; ++sct) {
            int o = (sct * 256 + tid) * 16;
            int r = o >> 8;
            int gr = r0 + r; if (gr > M - 1) gr = M - 1;
            uint4 val = *reinterpret_cast<const uint4*>(Asrc + (size_t)gr * 256 + (o & 255));
            *reinterpret_cast<uint4*>(sA + (o ^ ((r & 7) << 4))) = val;
        }
    }
    #pragma unroll
    for (int sct = 0; sct < 8; ++sct) {
        int o = (sct * 256 + tid) * 16;
        int r = o >> 8;
        uint4 val = *reinterpret_cast<const uint4*>(Wb + o);
        *reinterpret_cast<uint4*>(sB + (o ^ ((r & 7) << 4))) = val;
    }
    __syncthreads();

    const int lane = tid & 63, wid = tid >> 6;
    const int wm = wid >> 1, wn = wid & 1;
    const int qw = lane >> 4, c16 = lane & 15;

    f32x4 acc[4][4];
    #pragma unroll
    for (int a = 0; a < 4; ++a)
        #pragma unroll
        for (int b = 0; b < 4; ++b) acc[a][b] = (f32x4){0.f, 0.f, 0.f, 0.f};

    int aoff[4], boff[4];
    #pragma unroll
    for (int fm = 0; fm < 4; ++fm) {
        int r = wm * 64 + fm * 16 + c16;
        aoff[fm] = r * 256 + ((qw * 16) ^ ((r & 7) << 4));
    }
    #pragma unroll
    for (int fn = 0; fn < 4; ++fn) {
        int r = wn * 64 + fn * 16 + c16;
        boff[fn] = r * 256 + ((qw * 16) ^ ((r & 7) << 4));
    }

    #pragma unroll
    for (int ks = 0; ks < 4; ++ks) {
        const int kx = ks * 64;
        bf16x8 af[4], bfr[4];
        #pragma unroll
        for (int fm = 0; fm < 4; ++fm)
            af[fm] = *reinterpret_cast<const bf16x8*>(sA + (aoff[fm] ^ kx));
        #pragma unroll
        for (int fn = 0; fn < 4; ++fn)
            bfr[fn] = *reinterpret_cast<const bf16x8*>(sB + (boff[fn] ^ kx));
        #pragma unroll
        for (int fm = 0; fm < 4; ++fm)
            #pragma unroll
            for (int fn = 0; fn < 4; ++fn)
                acc[fm][fn] = __builtin_amdgcn_mfma_f32_16x16x32_bf16(
                    af[fm], bfr[fn], acc[fm][fn], 0, 0, 0);
    }

    #pragma unroll
    for (int fn = 0; fn < 4; ++fn) {
        int colbase = c0 + wn * 64 + fn * 16;
        int g = colbase / 96;
        unsigned short* obuf; int elem0;
        if (g == 0)      { obuf = qsb;  elem0 = colbase; }
        else if (g == 3) { obuf = qsb;  elem0 = colbase - 192; }
        else             { obuf = aggb; elem0 = colbase - 96; }
        float bcol = bias[colbase + c16];
        #pragma unroll
        for (int fm = 0; fm < 4; ++fm) {
            #pragma unroll
            for (int j = 0; j < 4; ++j) {
                int rg = r0 + wm * 64 + fm * 16 + qw * 4 + j;
                float o = acc[fm][fn][j] + bcol;
                float o2 = __shfl_xor(o, 1);
                if (!(lane & 1) && rg < M) {
                    *reinterpret_cast<unsigned int*>(
                        (char*)obuf + (size_t)rg * 384 + (size_t)(elem0 + c16) * 2) = pk2(o, o2);
                }
            }
        }
    }
}

// ---------------------------------------------------------------------------
// Setup: blocks 0-191 pack layer-1 weights, 192-383 layer-2, 384+ histogram
// of dst into NBKT coarse buckets (LDS-aggregated).
// ---------------------------------------------------------------------------
__global__ __launch_bounds__(256) void setup_kernel(
    const float* __restrict__ w0a, const float* __restrict__ w1a,
    const float* __restrict__ w2a, const float* __restrict__ w3a,
    const float* __restrict__ b0a, const float* __restrict__ b1a,
    const float* __restrict__ b2a, const float* __restrict__ b3a,
    const float* __restrict__ w0b, const float* __restrict__ w1b,
    const float* __restrict__ w2b, const float* __restrict__ w3b,
    const float* __restrict__ b0b, const float* __restrict__ b1b,
    const float* __restrict__ b2b, const float* __restrict__ b3b,
    const int* __restrict__ dst,
    unsigned short* __restrict__ WtA, float* __restrict__ b4a,
    unsigned short* __restrict__ WtB, float* __restrict__ b4b,
    int* __restrict__ bucketCnt)
{
    __shared__ int hist[NBKT];
    const int tid = threadIdx.x;
    const int blk = blockIdx.x;
    if (blk < 384) {
        const bool L2w = blk >= 192;
        int idx = (L2w ? blk - 192 : blk) * 256 + tid;   // < 384*128
        int n = idx >> 7, k = idx & 127;
        int g = n / 96, c = n - g * 96;
        const float* w; const float* bb;
        if (!L2w) {
            w = (g == 0) ? w0a : (g == 1) ? w1a : (g == 2) ? w2a : w3a;
            bb = (g == 0) ? b0a : (g == 1) ? b1a : (g == 2) ? b2a : b3a;
            WtA[idx] = bf16rne((k < 128) ? w[(size_t)k * 96 + c] : 0.f);
            if (k == 0) b4a[n] = bb[c];
        } else {
            w = (g == 0) ? w0b : (g == 1) ? w1b : (g == 2) ? w2b : w3b;
            bb = (g == 0) ? b0b : (g == 1) ? b1b : (g == 2) ? b2b : b3b;
            WtB[idx] = bf16rne((k < 96) ? w[(size_t)k * 96 + c] : 0.f);
            if (k == 0) b4b[n] = bb[c];
        }
    } else {
        const int hb = blk - 384;
        for (int t = tid; t < NBKT; t += 256) hist[t] = 0;
        __syncthreads();
        const int e0 = hb * E_PER_BLK;
        const int ne = min(E_PER_BLK, NE_C - e0);
        for (int j = tid; j < ne; j += 256)
            atomicAdd(&hist[((unsigned)dst[e0 + j]) >> 8], 1);
        __syncthreads();
        for (int t = tid; t < NBKT; t += 256)
            if (hist[t]) atomicAdd(&bucketCnt[t], hist[t]);
    }
}

// ---------------------------------------------------------------------------
// 1-block scan of bucket counts -> bucketBase[NBKT+1], gCur init.
// ---------------------------------------------------------------------------
__global__ __launch_bounds__(256) void scanb_kernel(
    const int* __restrict__ bucketCnt, int* __restrict__ bucketBase,
    int* __restrict__ gCur)
{
    __shared__ int ws[4];
    const int tid = threadIdx.x;
    int v = (tid < NBKT) ? bucketCnt[tid] : 0;
    int incl = block_incl_scan(v, tid & 63, tid >> 6, ws);
    int excl = incl - v;
    if (tid < NBKT) { bucketBase[tid] = excl; gCur[tid] = excl; }
    if (tid == NBKT - 1) bucketBase[NBKT] = incl;
}

// ---------------------------------------------------------------------------
// Stage 1: bin edges into coarse buckets with LDS staging; per-bucket runs
// written coalesced to bktArr (packed (dst<<16)|src).
// ---------------------------------------------------------------------------
__global__ __launch_bounds__(256) void stage1_kernel(
    const int* __restrict__ src, const int* __restrict__ dst,
    int* __restrict__ gCur, unsigned int* __restrict__ bktArr)
{
    __shared__ int hist[NBKT], loff[NBKT], lcur[NBKT], gbase[NBKT];
    __shared__ unsigned int bufRaw[E_PER_BLK];
    __shared__ unsigned int buf[E_PER_BLK];
    __shared__ int ws[4];
    const int tid = threadIdx.x;
    const int e0 = blockIdx.x * E_PER_BLK;
    const int ne = min(E_PER_BLK, NE_C - e0);

    for (int t = tid; t < NBKT; t += 256) hist[t] = 0;
    __syncthreads();
    for (int j = tid; j < ne; j += 256) {
        int d = dst[e0 + j], s = src[e0 + j];
        unsigned int pk = ((unsigned)d << 16) | (unsigned)s;
        bufRaw[j] = pk;
        atomicAdd(&hist[(unsigned)d >> 8], 1);
    }
    __syncthreads();
    {
        int v = (tid < NBKT) ? hist[tid] : 0;
        int incl = block_incl_scan(v, tid & 63, tid >> 6, ws);
        if (tid < NBKT) { loff[tid] = incl - v; lcur[tid] = incl - v; }
    }
    __syncthreads();
    for (int j = tid; j < ne; j += 256) {
        unsigned int pk = bufRaw[j];
        int p = atomicAdd(&lcur[pk >> 24], 1);
        buf[p] = pk;
    }
    __syncthreads();
    if (tid < NBKT && hist[tid] > 0) gbase[tid] = atomicAdd(&gCur[tid], hist[tid]);
    __syncthreads();
    for (int j = tid; j < ne; j += 256) {
        unsigned int pk = buf[j];
        int b = pk >> 24;
        bktArr[gbase[b] + (j - loff[b])] = pk;
    }
}

// ---------------------------------------------------------------------------
// Stage 2: one block per bucket -> exact per-node CSR in LDS, coalesced
// writes of csrb (src*384 byte offsets) and row offsets.
// ---------------------------------------------------------------------------
__global__ __launch_bounds__(256) void stage2_kernel(
    const unsigned int* __restrict__ bktArr, const int* __restrict__ bucketBase,
    int* __restrict__ csrb, int* __restrict__ row)
{
    __shared__ int ncnt[256], noff[256], ncur[256];
    __shared__ int outb[S2_CAP];
    __shared__ int ws[4];
    const int tid = threadIdx.x;
    const int b = blockIdx.x;
    const int base = bucketBase[b];
    const int cnt = bucketBase[b + 1] - base;

    ncnt[tid] = 0;
    __syncthreads();
    for (int j = tid; j < cnt; j += 256)
        atomicAdd(&ncnt[(bktArr[base + j] >> 16) & 255], 1);
    __syncthreads();
    {
        int v = ncnt[tid];
        int incl = block_incl_scan(v, tid & 63, tid >> 6, ws);
        noff[tid] = incl - v; ncur[tid] = incl - v;
    }
    __syncthreads();
    for (int j = tid; j < cnt; j += 256) {
        unsigned int pk = bktArr[base + j];
        int p = atomicAdd(&ncur[(pk >> 16) & 255], 1);
        if (p < S2_CAP) outb[p] = (int)(pk & 0xFFFFu) * 384;   // src * row bytes
    }
    __syncthreads();
    for (int j = tid; j < cnt && j < S2_CAP; j += 256) csrb[base + j] = outb[j];
    const int node0 = b * 256;
    if (node0 + tid < NN_C) row[node0 + tid] = base + noff[tid];
    if (b == 0 && tid == 0) row[NN_C] = NE_C;
}

// ---------------------------------------------------------------------------
// Fused attention aggregate, quarter-wave edge mapping.
// agg[n][192]=k|v bf16 (384 B rows), qs[n][192]=q|s bf16.
// Each 16-lane quarter owns one edge; lane l covers dims 6l..6l+5 (12 B
// dwordx3 gathers for k and v). 4 edges/wave/iter, 4 shuffle stages total,
// max-free softmax (q pre-scaled). csrb holds src*384 byte offsets.
// MODE 0: relu + bf16[128] zero-padded out (next layer's A).
// MODE 1: fused head -> d_out[n][32] f32 = (o+skip) @ Wd + bd.
// Grid must satisfy grid*4 == nnodes exactly (no early return).
// ---------------------------------------------------------------------------
template<int MODE>
__global__ __launch_bounds__(256) void aggregate_kernel(
    const unsigned short* __restrict__ aggb, const unsigned short* __restrict__ qsb,
    const int* __restrict__ row, const int* __restrict__ csrb,
    const float* __restrict__ Wd, const float* __restrict__ bd,
    void* __restrict__ outv, int nnodes)
{
    __shared__ float headL[MODE == 1 ? (96 * 32 + 32 + 4 * 96) : 1];
    const int tid  = threadIdx.x;
    const int wid  = tid >> 6;
    const int lane = tid & 63;
    const int l = lane & 15;      // dim slot: dims 6l..6l+5
    const int q = lane >> 4;      // quarter id (edge selector)
    const int n = blockIdx.x * 4 + wid;

    if constexpr (MODE == 1) {
        // stage Wd+bd BEFORE the edge loop: waves are still in lockstep here,
        // so this barrier costs nothing (the old post-loop barrier stalled on
        // per-wave edge-count imbalance).
        #pragma unroll
        for (int t = 0; t < 12; ++t) headL[t * 256 + tid] = Wd[t * 256 + tid];
        if (tid < 32) headL[3072 + tid] = bd[tid];
        __syncthreads();
    }

    const float scale = 0.10206207261596577f;   // 1/sqrt(96)
    const char* AG = (const char*)aggb;
    const char* QS = (const char*)qsb;
    const size_t qrb = (size_t)n * 384;

    // q dims 6l..6l+5, pre-scaled
    U3 qd = *(const U3*)(QS + qrb + 12 * l);
    const float q0 = blo(qd.x) * scale, q1 = bhi(qd.x) * scale;
    const float q2 = blo(qd.y) * scale, q3 = bhi(qd.y) * scale;
    const float q4 = blo(qd.z) * scale, q5 = bhi(qd.z) * scale;

    const char* AGk = AG + 12 * l;         // k dims 6l..6l+5 at row+12l
    const char* AGv = AG + 192 + 12 * l;   // v dims 6l..6l+5

    float s = 0.f, a0 = 0.f, a1 = 0.f, a2 = 0.f, a3 = 0.f, a4 = 0.f, a5 = 0.f;
    const int beg = row[n], end = row[n + 1];

    auto quad = [&](int i0) {
        const int base = csrb[i0 + q];
        U3 kd = *(const U3*)(AGk + base);
        U3 vd = *(const U3*)(AGv + base);
        float p = q0 * blo(kd.x) + q1 * bhi(kd.x) + q2 * blo(kd.y)
                + q3 * bhi(kd.y) + q4 * blo(kd.z) + q5 * bhi(kd.z);
        #pragma unroll
        for (int off = 1; off < 16; off <<= 1) p += __shfl_xor(p, off);
        float e = __expf(p);
        s  += e;
        a0 += e * blo(vd.x); a1 += e * bhi(vd.x);
        a2 += e * blo(vd.y); a3 += e * bhi(vd.y);
        a4 += e * blo(vd.z); a5 += e * bhi(vd.z);
    };

    int i = beg;
    for (; i + 8 <= end; i += 8) { quad(i); quad(i + 4); }
    for (; i + 4 <= end; i += 4) quad(i);
    if (i < end) {
        const int j = i + q;
        const int jc = (j < end) ? j : (end - 1);
        const int base = csrb[jc];
        U3 kd = *(const U3*)(AGk + base);
        U3 vd = *(const U3*)(AGv + base);
        float p = q0 * blo(kd.x) + q1 * bhi(kd.x) + q2 * blo(kd.y)
                + q3 * bhi(kd.y) + q4 * blo(kd.z) + q5 * bhi(kd.z);
        #pragma unroll
        for (int off = 1; off < 16; off <<= 1) p += __shfl_xor(p, off);
        float e = (j < end) ? __expf(p) : 0.f;
        s  += e;
        a0 += e * blo(vd.x); a1 += e * bhi(vd.x);
        a2 += e * blo(vd.y); a3 += e * bhi(vd.y);
        a4 += e * blo(vd.z); a5 += e * bhi(vd.z);
    }
    // combine the four quarters (each lane keeps its dim slot l)
    #pragma unroll
    for (int off = 16; off < 64; off <<= 1) {
        s  += __shfl_xor(s, off);
        a0 += __shfl_xor(a0, off); a1 += __shfl_xor(a1, off);
        a2 += __shfl_xor(a2, off); a3 += __shfl_xor(a3, off);
        a4 += __shfl_xor(a4, off); a5 += __shfl_xor(a5, off);
    }
    const float inv = 1.0f / (s + 1e-16f);

    // skip dims 6l..6l+5
    U3 sd = *(const U3*)(QS + qrb + 192 + 12 * l);
    float o0 = a0 * inv + blo(sd.x), o1 = a1 * inv + bhi(sd.x);
    float o2 = a2 * inv + blo(sd.y), o3 = a3 * inv + bhi(sd.y);
    float o4 = a4 * inv + blo(sd.z), o5 = a5 * inv + bhi(sd.z);

    if constexpr (MODE == 0) {
        o0 = fmaxf(o0, 0.f); o1 = fmaxf(o1, 0.f); o2 = fmaxf(o2, 0.f);
        o3 = fmaxf(o3, 0.f); o4 = fmaxf(o4, 0.f); o5 = fmaxf(o5, 0.f);
        char* O = (char*)outv;
        const size_t ob = (size_t)n * 256;
        if (q < 3) {
            // quarter q writes dword (dims 6l+2q, 6l+2q+1): covers bytes 0..191
            float u0 = (q == 0) ? o0 : (q == 1) ? o2 : o4;
            float u1 = (q == 0) ? o1 : (q == 1) ? o3 : o5;
            *(unsigned int*)(O + ob + 12 * l + 4 * q) = pk2(u0, u1);
        } else {
            *(unsigned int*)(O + ob + 192 + 4 * l) = 0u;   // zero-pad dims 96-127
        }
    } else {
        // stage o[96] into this wave's LDS slot (same-wave write->read, no barrier)
        float* oW = headL + 3104 + wid * 96;
        if (q == 0) {
            oW[6 * l + 0] = o0; oW[6 * l + 1] = o1; oW[6 * l + 2] = o2;
            oW[6 * l + 3] = o3; oW[6 * l + 4] = o4; oW[6 * l + 5] = o5;
        }
        const int c = lane & 31, h = lane >> 5;
        const int d0 = h * 48;
        float acc = 0.f;
        #pragma unroll
        for (int d = 0; d < 48; ++d)
            acc += oW[d0 + d] * headL[(d0 + d) * 32 + c];
        acc += __shfl_xor(acc, 32);
        if (lane < 32)
            ((float*)outv)[(size_t)n * 32 + c] = acc + headL[3072 + c];
    }
}

// ---------------------------------------------------------------------------
extern "C" void kernel_launch(void* const* d_in, const int* in_sizes, int n_in,
                              void* d_out, int out_size, void* d_ws, size_t ws_size,
                              hipStream_t stream)
{
    const int NN = NN_C, NE = NE_C;
    const float* x  = (const float*)d_in[0];
    const int*   ei = (const int*)d_in[1];
    const int* src = ei;
    const int* dst = ei + NE;

    const float* Wq1 = (const float*)d_in[2];  const float* bq1 = (const float*)d_in[3];
    const float* Wk1 = (const float*)d_in[4];  const float* bk1 = (const float*)d_in[5];
    const float* Wv1 = (const float*)d_in[6];  const float* bv1 = (const float*)d_in[7];
    const float* Ws1 = (const float*)d_in[8];  const float* bs1 = (const float*)d_in[9];
    const float* Wq2 = (const float*)d_in[10]; const float* bq2 = (const float*)d_in[11];
    const float* Wk2 = (const float*)d_in[12]; const float* bk2 = (const float*)d_in[13];
    const float* Wv2 = (const float*)d_in[14]; const float* bv2 = (const float*)d_in[15];
    const float* Ws2 = (const float*)d_in[16]; const float* bs2 = (const float*)d_in[17];
    const float* Wd  = (const float*)d_in[18]; const float* bd  = (const float*)d_in[19];

    char* base = (char*)d_ws;
    size_t off = 0;
    auto alloc = [&](size_t bytes) -> void* {
        void* p = base + off;
        off += (bytes + 255) & ~(size_t)255;
        return p;
    };
    unsigned short* aggb   = (unsigned short*)alloc((size_t)NN * 192 * 2);  // k|v
    unsigned short* qsb    = (unsigned short*)alloc((size_t)NN * 192 * 2);  // q|s
    unsigned short* hb16   = (unsigned short*)alloc((size_t)NN * 128 * 2);
    unsigned short* Wt4a   = (unsigned short*)alloc(384 * 128 * 2);
    unsigned short* Wt4b   = (unsigned short*)alloc(384 * 128 * 2);
    float*          b4a    = (float*)alloc(384 * 4);
    float*          b4b    = (float*)alloc(384 * 4);
    int*            bucketCnt  = (int*)alloc(NBKT * 4);
    int*            bucketBase = (int*)alloc((NBKT + 1) * 4);
    int*            gCur   = (int*)alloc(NBKT * 4);
    unsigned int*   bktArr = (unsigned int*)alloc((size_t)NE * 4);
    int*            csrb   = (int*)alloc((size_t)NE * 4);
    int*            rowp   = (int*)alloc((NN + 1) * 4);

    // ---- CSR build + weight packing (fused)
    hipMemsetAsync(bucketCnt, 0, NBKT * sizeof(int), stream);
    setup_kernel<<<384 + S1_BLOCKS, 256, 0, stream>>>(
        Wq1, Wk1, Wv1, Ws1, bq1, bk1, bv1, bs1,
        Wq2, Wk2, Wv2, Ws2, bq2, bk2, bv2, bs2,
        dst, Wt4a, b4a, Wt4b, b4b, bucketCnt);
    scanb_kernel<<<1, 256, 0, stream>>>(bucketCnt, bucketBase, gCur);
    stage1_kernel<<<S1_BLOCKS, 256, 0, stream>>>(src, dst, gCur, bktArr);
    stage2_kernel<<<NBKT, 256, 0, stream>>>(bktArr, bucketBase, csrb, rowp);

    dim3 blk(256);
    dim3 gg((NN + 127) / 128, 3);
    const int aggGrid = NN / 4;   // exact: 50000 = 12500*4 (no early return)

    // ---- layer 1 (A = fp32 x, converted during staging)
    gemm_mfma<true><<<gg, blk, 0, stream>>>(x, Wt4a, b4a, aggb, qsb, NN);
    aggregate_kernel<0><<<aggGrid, blk, 0, stream>>>(
        aggb, qsb, rowp, csrb, nullptr, nullptr, hb16, NN);

    // ---- layer 2 (A = bf16, K zero-padded 96->128) + fused head -> d_out
    gemm_mfma<false><<<gg, blk, 0, stream>>>(hb16, Wt4b, b4b, aggb, qsb, NN);
    aggregate_kernel<1><<<aggGrid, blk, 0, stream>>>(
        aggb, qsb, rowp, csrb, Wd, bd, d_out, NN);
}